// Round 18
// baseline (460.337 us; speedup 1.0000x reference)
//
#include <hip/hip_runtime.h>

// Problem constants (fixed by the reference file)
#define NND 50000   // nodes
#define NE  600000  // edges
#define TSEQ 50     // sequence length
#define NB  1000    // batch = NND/TSEQ
#define SB  4       // sequences per LSTM workgroup
#define AHS 136     // LDS h-row stride in shorts (128 + 8 pad, 16B-aligned)
#define NSCB 196    // scan blocks: ceil(NND/256)

typedef __attribute__((ext_vector_type(4))) float f32x4;
typedef __attribute__((ext_vector_type(8))) short s16x8;

// ---------------------------------------------------------------- helpers
// Fast activations: raw v_rcp_f32 (~1 ulp); error 3 orders below the proven
// absmax-free bf16 noise floor (R11-R17).
__device__ __forceinline__ float sigf(float x) {
    return __builtin_amdgcn_rcpf(1.0f + __expf(-x));
}
__device__ __forceinline__ float tanhfast(float x) {
    x = fminf(fmaxf(x, -15.f), 15.f);
    float e = __expf(2.f * x);
    return (e - 1.f) * __builtin_amdgcn_rcpf(e + 1.f);
}
// bf16 bit helpers (round-to-nearest-even)
__device__ __forceinline__ unsigned short f2bf(float f) {
    unsigned int u = __float_as_uint(f);
    u = u + 0x7FFFu + ((u >> 16) & 1u);
    return (unsigned short)(u >> 16);
}
__device__ __forceinline__ float bf2f(unsigned short h) {
    return __uint_as_float(((unsigned int)h) << 16);
}
// LDS-only barrier: waits DS ops (lgkmcnt) but leaves GLOBAL ops in flight.
__device__ __forceinline__ void barrier_lds_only() {
    asm volatile("s_waitcnt lgkmcnt(0)\n\ts_barrier" ::: "memory");
}
// G row permutation: node n -> block-local row (blk*200 + step*4 + seq_in_blk).
__device__ __forceinline__ int grow_perm(int n) {
    int grp = n / 200;
    int rem = n % 200;
    return grp * 200 + (n % 50) * 4 + rem / 50;
}

// ---------------------------------------------------------------- CSR build
__global__ void k_count(const int* __restrict__ ei, int* __restrict__ cnt) {
    int e = blockIdx.x * 256 + threadIdx.x;
    if (e < NE) atomicAdd(&cnt[ei[NE + e]], 1);
}

// ---- 3-stage multi-block exclusive scan of cnt -> rowstart (+ fused dinv)
__global__ __launch_bounds__(256) void k_bsum(const int* __restrict__ cnt,
                                              int* __restrict__ bsum) {
    __shared__ int red[256];
    int t = threadIdx.x;
    int idx = blockIdx.x * 256 + t;
    red[t] = (idx < NND) ? cnt[idx] : 0;
    __syncthreads();
    for (int off = 128; off > 0; off >>= 1) {
        if (t < off) red[t] += red[t + off];
        __syncthreads();
    }
    if (t == 0) bsum[blockIdx.x] = red[0];
}

__global__ __launch_bounds__(256) void k_bscan(int* __restrict__ bsum) {
    __shared__ int ps[256];
    int t = threadIdx.x;
    int v = (t < NSCB) ? bsum[t] : 0;
    ps[t] = v;
    __syncthreads();
    for (int off = 1; off < 256; off <<= 1) {
        int u = 0;
        if (t >= off) u = ps[t - off];
        __syncthreads();
        if (t >= off) ps[t] += u;
        __syncthreads();
    }
    if (t < NSCB) bsum[t] = ps[t] - v;   // exclusive
}

__global__ __launch_bounds__(256) void k_bout(const int* __restrict__ cnt,
                                              const int* __restrict__ bsum,
                                              int* __restrict__ rowstart,
                                              float* __restrict__ dinv) {
    __shared__ int ps[256];
    int t = threadIdx.x;
    int idx = blockIdx.x * 256 + t;
    int v = (idx < NND) ? cnt[idx] : 0;
    ps[t] = v;
    __syncthreads();
    for (int off = 1; off < 256; off <<= 1) {
        int u = 0;
        if (t >= off) u = ps[t - off];
        __syncthreads();
        if (t >= off) ps[t] += u;
        __syncthreads();
    }
    int boff = bsum[blockIdx.x];
    if (idx < NND) {
        rowstart[idx] = boff + ps[t] - v;   // exclusive
        dinv[idx] = 1.0f / sqrtf((float)v + 1.0f);   // fused (was k_dinv)
    }
    if (idx == NND - 1) rowstart[NND] = boff + ps[t];  // == NE
}

__global__ void k_fill(const int* __restrict__ ei, const int* __restrict__ rowstart,
                       int* __restrict__ cursor, int* __restrict__ adj) {
    int e = blockIdx.x * 256 + threadIdx.x;
    if (e >= NE) return;
    int s = ei[e], d = ei[NE + e];
    int pos = atomicAdd(&cursor[d], 1);
    adj[rowstart[d] + pos] = s;
}

// ---------------------------------------------------------------- MFMA GEMM
// 2-term GCN GEMM: A plain bf16 (hi only), B split hi/lo. BF16 h output.
__global__ __launch_bounds__(256) void k_gemm_mfma_h2(
    const unsigned short* __restrict__ Ahi,
    const unsigned short* __restrict__ Bhi, const unsigned short* __restrict__ Blo,
    const float* __restrict__ bias, unsigned short* __restrict__ C,
    int M, int Nc, int NT)
{
    __shared__ unsigned short As_hi[128][136];

    const int tid  = threadIdx.x;
    const int lane = tid & 63, wave = tid >> 6;
    const int mw = wave & 1, nw = wave >> 1;
    const int l15 = lane & 15, quad = lane >> 4;
    const int rowBase = blockIdx.y * 128;

    {
        int r0 = tid >> 4;            // 0..15
        int ko = (tid & 15) * 8;      // 0..120
        #pragma unroll
        for (int i = 0; i < 8; ++i) {
            int row = r0 + i * 16;
            int g = rowBase + row;
            uint4 vh = make_uint4(0, 0, 0, 0);
            if (g < M) vh = *(const uint4*)&Ahi[(size_t)g * 128 + ko];
            *(uint4*)&As_hi[row][ko] = vh;
        }
    }
    __syncthreads();

    for (int nt = 0; nt < NT; ++nt) {
        const int colBase = (blockIdx.x * NT + nt) * 64;

        s16x8 bh[2][4], bl[2][4];   // [ns][kq]
        #pragma unroll
        for (int ns = 0; ns < 2; ++ns) {
            int gn = colBase + nw * 32 + ns * 16 + l15;
            #pragma unroll
            for (int kq = 0; kq < 4; ++kq) {
                bh[ns][kq] = *(const s16x8*)&Bhi[(size_t)gn * 128 + kq * 32 + quad * 8];
                bl[ns][kq] = *(const s16x8*)&Blo[(size_t)gn * 128 + kq * 32 + quad * 8];
            }
        }

        f32x4 acc[4][2] = {};
        #pragma unroll
        for (int kq = 0; kq < 4; ++kq) {
            int kof = kq * 32 + quad * 8;
            s16x8 ah[4];
            #pragma unroll
            for (int ms = 0; ms < 4; ++ms) {
                int r = mw * 64 + ms * 16 + l15;
                ah[ms] = *(const s16x8*)&As_hi[r][kof];
            }
            #pragma unroll
            for (int ms = 0; ms < 4; ++ms)
                #pragma unroll
                for (int ns = 0; ns < 2; ++ns)
                    acc[ms][ns] = __builtin_amdgcn_mfma_f32_16x16x32_bf16(ah[ms], bh[ns][kq], acc[ms][ns], 0, 0, 0);
            #pragma unroll
            for (int ms = 0; ms < 4; ++ms)
                #pragma unroll
                for (int ns = 0; ns < 2; ++ns)
                    acc[ms][ns] = __builtin_amdgcn_mfma_f32_16x16x32_bf16(ah[ms], bl[ns][kq], acc[ms][ns], 0, 0, 0);
        }

        #pragma unroll
        for (int ns = 0; ns < 2; ++ns) {
            int col = colBase + nw * 32 + ns * 16 + l15;
            float bv = bias ? bias[col] : 0.f;
            #pragma unroll
            for (int ms = 0; ms < 4; ++ms) {
                int row0 = rowBase + mw * 64 + ms * 16 + quad * 4;
                #pragma unroll
                for (int r = 0; r < 4; ++r) {
                    int row = row0 + r;
                    if (row < M) C[(size_t)row * Nc + col] = f2bf(acc[ms][ns][r] + bv);
                }
            }
        }
    }
}

// Variant: A is raw fp32 (input x); split-bf16 conversion fused into staging.
// BF16 h output.
__global__ __launch_bounds__(256) void k_gemm_mfma_xa(
    const float* __restrict__ X,
    const unsigned short* __restrict__ Bhi, const unsigned short* __restrict__ Blo,
    const float* __restrict__ bias, unsigned short* __restrict__ C,
    int M, int Nc, int NT)
{
    __shared__ unsigned short As_hi[128][136];
    __shared__ unsigned short As_lo[128][136];

    const int tid  = threadIdx.x;
    const int lane = tid & 63, wave = tid >> 6;
    const int mw = wave & 1, nw = wave >> 1;
    const int l15 = lane & 15, quad = lane >> 4;
    const int rowBase = blockIdx.y * 128;

    {
        int r0 = tid >> 4;
        int ko = (tid & 15) * 8;
        #pragma unroll
        for (int i = 0; i < 8; ++i) {
            int row = r0 + i * 16;
            int g = rowBase + row;
            unsigned short hx[8], lx[8];
            if (g < M) {
                float4 v0 = *(const float4*)&X[(size_t)g * 128 + ko];
                float4 v1 = *(const float4*)&X[(size_t)g * 128 + ko + 4];
                const float vv[8] = {v0.x, v0.y, v0.z, v0.w, v1.x, v1.y, v1.z, v1.w};
                #pragma unroll
                for (int e = 0; e < 8; ++e) {
                    hx[e] = f2bf(vv[e]);
                    lx[e] = f2bf(vv[e] - bf2f(hx[e]));
                }
            } else {
                #pragma unroll
                for (int e = 0; e < 8; ++e) { hx[e] = 0; lx[e] = 0; }
            }
            *(uint4*)&As_hi[row][ko] = *(const uint4*)hx;
            *(uint4*)&As_lo[row][ko] = *(const uint4*)lx;
        }
    }
    __syncthreads();

    for (int nt = 0; nt < NT; ++nt) {
        const int colBase = (blockIdx.x * NT + nt) * 64;

        s16x8 bh[2][4], bl[2][4];
        #pragma unroll
        for (int ns = 0; ns < 2; ++ns) {
            int gn = colBase + nw * 32 + ns * 16 + l15;
            #pragma unroll
            for (int kq = 0; kq < 4; ++kq) {
                bh[ns][kq] = *(const s16x8*)&Bhi[(size_t)gn * 128 + kq * 32 + quad * 8];
                bl[ns][kq] = *(const s16x8*)&Blo[(size_t)gn * 128 + kq * 32 + quad * 8];
            }
        }

        f32x4 acc[4][2] = {};
        #pragma unroll
        for (int kq = 0; kq < 4; ++kq) {
            int kof = kq * 32 + quad * 8;
            s16x8 ah[4], al[4];
            #pragma unroll
            for (int ms = 0; ms < 4; ++ms) {
                int r = mw * 64 + ms * 16 + l15;
                ah[ms] = *(const s16x8*)&As_hi[r][kof];
                al[ms] = *(const s16x8*)&As_lo[r][kof];
            }
            #pragma unroll
            for (int ms = 0; ms < 4; ++ms)
                #pragma unroll
                for (int ns = 0; ns < 2; ++ns)
                    acc[ms][ns] = __builtin_amdgcn_mfma_f32_16x16x32_bf16(ah[ms], bh[ns][kq], acc[ms][ns], 0, 0, 0);
            #pragma unroll
            for (int ms = 0; ms < 4; ++ms)
                #pragma unroll
                for (int ns = 0; ns < 2; ++ns)
                    acc[ms][ns] = __builtin_amdgcn_mfma_f32_16x16x32_bf16(al[ms], bh[ns][kq], acc[ms][ns], 0, 0, 0);
            #pragma unroll
            for (int ms = 0; ms < 4; ++ms)
                #pragma unroll
                for (int ns = 0; ns < 2; ++ns)
                    acc[ms][ns] = __builtin_amdgcn_mfma_f32_16x16x32_bf16(ah[ms], bl[ns][kq], acc[ms][ns], 0, 0, 0);
        }

        #pragma unroll
        for (int ns = 0; ns < 2; ++ns) {
            int col = colBase + nw * 32 + ns * 16 + l15;
            float bv = bias ? bias[col] : 0.f;
            #pragma unroll
            for (int ms = 0; ms < 4; ++ms) {
                int row0 = rowBase + mw * 64 + ms * 16 + quad * 4;
                #pragma unroll
                for (int r = 0; r < 4; ++r) {
                    int row = row0 + r;
                    if (row < M) C[(size_t)row * Nc + col] = f2bf(acc[ms][ns][r] + bv);
                }
            }
        }
    }
}

// ---------------------------------------------------------------- gate GEMM v10
// 8-WAVE blocks (this round). R17 counters: occupancy 12.5% = 1 block/CU =
// 1 wave/SIMD -> zero TLP, per-wave 256-MFMA dependency chain was the wall.
// Now 512 thr / 8 waves, each wave owns 64 p-cols (2 tp tiles, 128 MFMAs):
// 2 waves/SIMD co-resident interleave latency; per-wave serial work halved.
// All W frags loaded upfront (before the staging barrier). Per-element
// accumulation order unchanged -> bit-identical.
__global__ __launch_bounds__(512, 1) void k_gemm_gT_h(
    const unsigned short* __restrict__ Ahi,
    const unsigned short* __restrict__ Whi, const unsigned short* __restrict__ Wlo,
    const float* __restrict__ bp, unsigned short* __restrict__ G,
    int M)
{
    __shared__ unsigned short As_hi[64][136];

    const int tid  = threadIdx.x;
    const int lane = tid & 63, wave = tid >> 6;   // 8 waves
    const int l15 = lane & 15, quad = lane >> 4;
    const int rowBase = blockIdx.x * 64;
    const int pb = wave * 64;                     // wave's 64 gate-cols

    // W fragments for both tp tiles, issued BEFORE the staging barrier
    s16x8 wh[2][2][4], wl[2][2][4];   // [tp][t][kq]
    #pragma unroll
    for (int tp = 0; tp < 2; ++tp)
        #pragma unroll
        for (int t = 0; t < 2; ++t)
            #pragma unroll
            for (int kq = 0; kq < 4; ++kq) {
                const size_t wrow = (size_t)(pb + tp * 32 + t * 16 + l15) * 128 + kq * 32 + quad * 8;
                wh[tp][t][kq] = *(const s16x8*)&Whi[wrow];
                wl[tp][t][kq] = *(const s16x8*)&Wlo[wrow];
            }

    // stage A (64 rows x 128 cols bf16): 8 threads/row, 2 x 16B chunks each
    {
        int r0 = tid >> 3;            // 0..63
        int ko = (tid & 7) * 8;       // 0..56 shorts
        int g = rowBase + r0;
        uint4 v0 = make_uint4(0, 0, 0, 0), v1 = make_uint4(0, 0, 0, 0);
        if (g < M) {
            v0 = *(const uint4*)&Ahi[(size_t)g * 128 + ko];
            v1 = *(const uint4*)&Ahi[(size_t)g * 128 + ko + 64];
        }
        *(uint4*)&As_hi[r0][ko] = v0;
        *(uint4*)&As_hi[r0][ko + 64] = v1;
    }
    __syncthreads();

    float4 bv[2][2];
    #pragma unroll
    for (int tp = 0; tp < 2; ++tp)
        #pragma unroll
        for (int t = 0; t < 2; ++t)
            bv[tp][t] = *(const float4*)&bp[pb + tp * 32 + t * 16 + quad * 4];

    #pragma unroll
    for (int tp = 0; tp < 2; ++tp) {
        const int p0 = pb + tp * 32;
        #pragma unroll
        for (int rg = 0; rg < 4; ++rg) {
            s16x8 xh[4];
            #pragma unroll
            for (int kq = 0; kq < 4; ++kq)
                xh[kq] = *(const s16x8*)&As_hi[rg * 16 + l15][kq * 32 + quad * 8];
            f32x4 acc[2] = {};
            #pragma unroll
            for (int kq = 0; kq < 4; ++kq)
                #pragma unroll
                for (int t = 0; t < 2; ++t) {
                    acc[t] = __builtin_amdgcn_mfma_f32_16x16x32_bf16(wh[tp][t][kq], xh[kq], acc[t], 0, 0, 0);
                    acc[t] = __builtin_amdgcn_mfma_f32_16x16x32_bf16(wl[tp][t][kq], xh[kq], acc[t], 0, 0, 0);
                }
            const int row = rowBase + rg * 16 + l15;
            if (row < M) {
                const size_t prow = (size_t)grow_perm(row);
                #pragma unroll
                for (int t = 0; t < 2; ++t) {
                    ushort4 o;
                    o.x = f2bf(acc[t][0] + bv[tp][t].x);
                    o.y = f2bf(acc[t][1] + bv[tp][t].y);
                    o.z = f2bf(acc[t][2] + bv[tp][t].z);
                    o.w = f2bf(acc[t][3] + bv[tp][t].w);
                    *(ushort4*)&G[prow * 512 + p0 + t * 16 + quad * 4] = o;
                }
            }
        }
    }
}

// ---------------------------------------------------------------- GCN gather
// h input BF16 (ushort2 per lane per edge). Edge loop unrolled x4;
// accumulation order preserved.
__global__ __launch_bounds__(256) void k_gather(
    const int* __restrict__ rowstart, const int* __restrict__ adj,
    const unsigned short* __restrict__ h, const float* __restrict__ dinv,
    const float* __restrict__ bias,
    unsigned short* __restrict__ hi)
{
    const int n    = blockIdx.x * 4 + (threadIdx.x >> 6);   // grid exactly NND/4
    const int lane = threadIdx.x & 63;
    const int r0 = rowstart[n], r1 = rowstart[n + 1];
    const float dn = dinv[n];

    ushort2 hv = *(const ushort2*)&h[(size_t)n * 128 + 2 * lane];
    float2 acc;
    acc.x = bf2f(hv.x) * dn;
    acc.y = bf2f(hv.y) * dn;

    int i = r0;
    for (; i + 4 <= r1; i += 4) {
        int s0 = adj[i], s1 = adj[i + 1], s2 = adj[i + 2], s3 = adj[i + 3];
        float d0 = dinv[s0], d1 = dinv[s1], d2 = dinv[s2], d3 = dinv[s3];
        ushort2 v0 = *(const ushort2*)&h[(size_t)s0 * 128 + 2 * lane];
        ushort2 v1 = *(const ushort2*)&h[(size_t)s1 * 128 + 2 * lane];
        ushort2 v2 = *(const ushort2*)&h[(size_t)s2 * 128 + 2 * lane];
        ushort2 v3 = *(const ushort2*)&h[(size_t)s3 * 128 + 2 * lane];
        acc.x += bf2f(v0.x) * d0; acc.y += bf2f(v0.y) * d0;
        acc.x += bf2f(v1.x) * d1; acc.y += bf2f(v1.y) * d1;
        acc.x += bf2f(v2.x) * d2; acc.y += bf2f(v2.y) * d2;
        acc.x += bf2f(v3.x) * d3; acc.y += bf2f(v3.y) * d3;
    }
    for (; i < r1; ++i) {
        int s = adj[i];
        float ds = dinv[s];
        ushort2 v = *(const ushort2*)&h[(size_t)s * 128 + 2 * lane];
        acc.x += bf2f(v.x) * ds;
        acc.y += bf2f(v.y) * ds;
    }

    float2 bb = *(const float2*)&bias[2 * lane];
    float vx = fmaxf(acc.x * dn + bb.x, 0.f);
    float vy = fmaxf(acc.y * dn + bb.y, 0.f);
    ushort2 ho;
    ho.x = f2bf(vx);
    ho.y = f2bf(vy);
    *(ushort2*)&hi[(size_t)n * 128 + 2 * lane] = ho;
}

// ---------------------------------------------------------------- prep kernels
__global__ void k_prep_gcnw2(const float* __restrict__ W1, const float* __restrict__ W2,
                             unsigned short* __restrict__ hi1, unsigned short* __restrict__ lo1,
                             unsigned short* __restrict__ hi2, unsigned short* __restrict__ lo2) {
    int t = blockIdx.x * 256 + threadIdx.x;   // grid 128 -> 32768 threads
    const float* W = (t < 16384) ? W1 : W2;
    unsigned short* hi = (t < 16384) ? hi1 : hi2;
    unsigned short* lo = (t < 16384) ? lo1 : lo2;
    int tt = t & 16383;
    int k = tt >> 7, n = tt & 127;
    float v = W[tt];
    unsigned short h = f2bf(v);
    hi[n * 128 + k] = h;
    lo[n * 128 + k] = f2bf(v - bf2f(h));
}

// LSTM prep: w_ih and w_hh [512(r=g*128+j)][128(k)] -> packed-transposed
// split-bf16 wT[p=j*4+g][k]; bias -> bp[p] = b_ih + b_hh.
__global__ void k_prep_lstm(const float* __restrict__ w_ih, const float* __restrict__ w_hh,
                            const float* __restrict__ b_ih, const float* __restrict__ b_hh,
                            unsigned short* __restrict__ ih_hi, unsigned short* __restrict__ ih_lo,
                            unsigned short* __restrict__ hh_hi, unsigned short* __restrict__ hh_lo,
                            float* __restrict__ bp)
{
    int t = blockIdx.x * 256 + threadIdx.x;
    if (t < 65536) {
        int r = t >> 7, k = t & 127;
        int g = r >> 7, j = r & 127;
        int p = (j << 2) + g;
        float v = w_ih[t];
        unsigned short h = f2bf(v);
        ih_hi[p * 128 + k] = h;
        ih_lo[p * 128 + k] = f2bf(v - bf2f(h));
    } else if (t < 131072) {
        int t2 = t - 65536;
        int r = t2 >> 7, k = t2 & 127;
        int g = r >> 7, j = r & 127;
        int p = (j << 2) + g;
        float v = w_hh[t2];
        unsigned short h = f2bf(v);
        hh_hi[p * 128 + k] = h;
        hh_lo[p * 128 + k] = f2bf(v - bf2f(h));
    } else if (t < 131584) {
        int r = t - 131072;   // 0..511
        int g = r >> 7, j = r & 127;
        bp[(j << 2) + g] = b_ih[r] + b_hh[r];
    }
}

// ---------------------------------------------------------------- LSTM recurrence
// v16 (verified R17): 1-term recurrence + bf16 G + LDS-only barrier + fast-rcp
// activations + bumped Hhi pointer + one-step G prefetch.
__global__ __launch_bounds__(512, 2) void k_lstm(
    const unsigned short* __restrict__ G,   // bf16, permuted: [blk][step][4 seq][512]
    const unsigned short* __restrict__ Whi, // 512 x 128, packed-transposed hi
    unsigned short* __restrict__ Hhi,       // (NB*TSEQ) x 128 bf16-hi, or nullptr
    const float* __restrict__ fcw,          // fused FC weight (layer 1) or nullptr
    const float* __restrict__ fcb,
    float* __restrict__ outp)               // NB x 1 output (layer 1) or nullptr
{
    const int tid  = threadIdx.x;
    const int lane = tid & 63, wave = tid >> 6;   // 8 waves
    const int l15  = lane & 15, quad = lane >> 4;
    const int b0   = blockIdx.x * SB;

    __shared__ __align__(16) unsigned short Ah[16 * AHS];  // h bf16 (rows SB..15 zero)
    __shared__ float partw[8][4][72];        // per-wave P patch [wave][b][col in wave]

    // weight fragments: wave owns n-tiles nt0..nt0+3 (n = p = j*4+gate)
    const int nt0 = wave * 4;
    s16x8 bh[4][4];   // [nt][ks]
    #pragma unroll
    for (int nt = 0; nt < 4; ++nt) {
        int p = (nt0 + nt) * 16 + l15;
        #pragma unroll
        for (int ks = 0; ks < 4; ++ks)
            bh[nt][ks] = *(const s16x8*)&Whi[(size_t)p * 128 + ks * 32 + quad * 8];
    }

    for (int i = tid; i < 16 * AHS; i += 512) Ah[i] = 0;

    // phase-2 mapping: lane l of wave w -> (b2, j) with j owned by wave w
    const int b2 = lane >> 4;              // 0..3
    const int jj = wave * 16 + l15;        // hidden unit this lane updates
    const int bg = b0 + b2;                // sequence index (NB % SB == 0)
    float c = 0.f;
    float hn_last = 0.f;

    // permuted-G base: row' = blk*200 + step*4 + b2; step stride = 2048 ushorts
    const unsigned short* gb = &G[((size_t)blockIdx.x * 200 + b2) * 512 + (jj << 2)];
    ushort4 gr_cur = *(const ushort4*)&gb[0];
    // hoisted Hhi pointer (bumped by 128 shorts per step)
    unsigned short* hptr = Hhi ? &Hhi[(size_t)bg * TSEQ * 128 + jj] : nullptr;

    __syncthreads();

    for (int step = 0; step < TSEQ; ++step) {
        // prefetch NEXT step's gate input (full step of latency cover;
        // NOT drained by the lds-only barrier below)
        const int nstep = (step + 1 < TSEQ) ? step + 1 : step;
        const ushort4 gr_nxt = *(const ushort4*)&gb[(size_t)nstep * 2048];

        // phase 1: MFMA  P = bf16(h) @ bf16(Whh)  (1-term)
        f32x4 acc[4] = {};
        #pragma unroll
        for (int ks = 0; ks < 4; ++ks) {
            s16x8 ah = *(const s16x8*)&Ah[l15 * AHS + ks * 32 + quad * 8];
            #pragma unroll
            for (int nt = 0; nt < 4; ++nt)
                acc[nt] = __builtin_amdgcn_mfma_f32_16x16x32_bf16(ah, bh[nt][ks], acc[nt], 0, 0, 0);
        }

        // intra-wave exchange: quad-0 lanes hold rows 0..3 (the real seqs)
        if (quad == 0) {
            #pragma unroll
            for (int nt = 0; nt < 4; ++nt)
                #pragma unroll
                for (int r = 0; r < 4; ++r)
                    partw[wave][r][nt * 16 + l15] = acc[nt][r];
        }
        // same-wave producer/consumer: compiler inserts lgkmcnt wait, no barrier

        // phase 2: LSTM cell for (b2, jj); reads this wave's own patch
        {
            float4 pa = *(const float4*)&partw[wave][b2][l15 * 4];
            float xi = pa.x + bf2f(gr_cur.x);
            float xf = pa.y + bf2f(gr_cur.y);
            float xg = pa.z + bf2f(gr_cur.z);
            float xo = pa.w + bf2f(gr_cur.w);
            float ii = sigf(xi), ff = sigf(xf), gg = tanhfast(xg), oo = sigf(xo);
            float cn = ff * c + ii * gg;
            c = cn;
            float hn = oo * tanhfast(cn);
            hn_last = hn;
            unsigned short hh = f2bf(hn);
            Ah[b2 * AHS + jj] = hh;
            if (hptr) {
                *hptr = hh;
                hptr += 128;
            }
        }
        gr_cur = gr_nxt;
        // LDS-only barrier: Ah writes visible to all waves; globals in flight
        barrier_lds_only();
    }

    // fused FC head (layer 1): out[bg] = dot(h_last[bg], fcw) + fcb
    if (outp) {
        float* red = (float*)Ah;   // 2 KiB scratch, Ah is dead now
        red[b2 * 128 + jj] = hn_last * fcw[jj];
        __syncthreads();
        if (wave < 4) {            // wave w reduces sequence b0+w
            float v = red[wave * 128 + lane] + red[wave * 128 + lane + 64];
            #pragma unroll
            for (int off = 32; off > 0; off >>= 1)
                v += __shfl_down(v, off);
            if (lane == 0) outp[b0 + wave] = v + fcb[0];
        }
    }
}

// ---------------------------------------------------------------- launch
extern "C" void kernel_launch(void* const* d_in, const int* in_sizes, int n_in,
                              void* d_out, int out_size, void* d_ws, size_t ws_size,
                              hipStream_t stream)
{
    const float* x    = (const float*)d_in[0];
    const int*   ei   = (const int*)d_in[1];
    const float* W1   = (const float*)d_in[3];
    const float* b1   = (const float*)d_in[4];
    const float* W2   = (const float*)d_in[5];
    const float* b2   = (const float*)d_in[6];
    const float* fcw  = (const float*)d_in[7];
    const float* fcb  = (const float*)d_in[8];
    const float* wih0 = (const float*)d_in[9];
    const float* whh0 = (const float*)d_in[10];
    const float* bih0 = (const float*)d_in[11];
    const float* bhh0 = (const float*)d_in[12];
    const float* wih1 = (const float*)d_in[13];
    const float* whh1 = (const float*)d_in[14];
    const float* bih1 = (const float*)d_in[15];
    const float* bhh1 = (const float*)d_in[16];
    float* out = (float*)d_out;

    char* ws = (char*)d_ws;
    // ---- persistent regions
    unsigned short* shi = (unsigned short*)(ws + 0);          // 12.8 MB
    unsigned short* bufG = (unsigned short*)(ws + 51200000);  // 51.2 MB bf16 (ends 102.4M)

    // ---- GCN-phase regions (overlap bufG region; dead before gate GEMM writes)
    unsigned short* xhi = (unsigned short*)(ws + 51200000);   // 12.8 MB
    unsigned short* bufHg = (unsigned short*)(ws + 76800000); // 12.8 MB bf16 h
    int* cnt      = (int*)(ws + 102400000);                   // 200000 B (pad 204800)
    int* cursor   = (int*)(ws + 102604800);                   // contiguous with cnt
    int* rowstart = (int*)(ws + 102809600);
    int* adj      = (int*)(ws + 103014400);                   // 2.4 MB (ends 105.42M)
    int* bsum     = (int*)(ws + 105420800);                   // NSCB ints

    float* dinv = (float*)(ws + 153600000);
    float* bp0  = (float*)(ws + 153800192);
    float* bp1  = (float*)(ws + 153802240);
    unsigned short* w1t_hi   = (unsigned short*)(ws + 153804288);
    unsigned short* w1t_lo   = (unsigned short*)(ws + 153837056);
    unsigned short* w2t_hi   = (unsigned short*)(ws + 153869824);
    unsigned short* w2t_lo   = (unsigned short*)(ws + 153902592);
    unsigned short* wpih0_hi = (unsigned short*)(ws + 153935360);
    unsigned short* wpih0_lo = (unsigned short*)(ws + 154066432);
    unsigned short* wpih1_hi = (unsigned short*)(ws + 154197504);
    unsigned short* wpih1_lo = (unsigned short*)(ws + 154328576);
    unsigned short* wphh0_hi = (unsigned short*)(ws + 154459648);
    unsigned short* wphh0_lo = (unsigned short*)(ws + 154590720);
    unsigned short* wphh1_hi = (unsigned short*)(ws + 154721792);
    unsigned short* wphh1_lo = (unsigned short*)(ws + 154852864);

    // ---- CSR build + dinv (multi-block scan); cnt+cursor zeroed in ONE memset
    hipMemsetAsync(cnt, 0, 409600, stream);
    k_count<<<(NE + 255) / 256, 256, 0, stream>>>(ei, cnt);
    k_bsum<<<NSCB, 256, 0, stream>>>(cnt, bsum);
    k_bscan<<<1, 256, 0, stream>>>(bsum);
    k_bout<<<NSCB, 256, 0, stream>>>(cnt, bsum, rowstart, dinv);
    k_fill<<<(NE + 255) / 256, 256, 0, stream>>>(ei, rowstart, cursor, adj);

    // ---- weight prep
    k_prep_gcnw2<<<128, 256, 0, stream>>>(W1, W2, w1t_hi, w1t_lo, w2t_hi, w2t_lo);
    k_prep_lstm<<<514, 256, 0, stream>>>(wih0, whh0, bih0, bhh0,
                                         wpih0_hi, wpih0_lo, wphh0_hi, wphh0_lo, bp0);
    k_prep_lstm<<<514, 256, 0, stream>>>(wih1, whh1, bih1, bhh1,
                                         wpih1_hi, wpih1_lo, wphh1_hi, wphh1_lo, bp1);

    dim3 gH(1, 391);     // GCN GEMMs: 128-row panel, NT=2 (128 cols)

    // ---- GCN layer 1 (fp32 A, convert-on-stage, split precision; bf16 h out)
    k_gemm_mfma_xa<<<gH, 256, 0, stream>>>(x, w1t_hi, w1t_lo, nullptr, bufHg, NND, 128, 2);
    k_gather<<<NND / 4, 256, 0, stream>>>(rowstart, adj, bufHg, dinv, b1, xhi);

    // ---- GCN layer 2 (2-term: A = bf16 hi only; bf16 h out)
    k_gemm_mfma_h2<<<gH, 256, 0, stream>>>(xhi, w2t_hi, w2t_lo, nullptr, bufHg, NND, 128, 2);
    k_gather<<<NND / 4, 256, 0, stream>>>(rowstart, adj, bufHg, dinv, b2, shi);

    // ---- LSTM layer 0: 8-wave 2-term gate GEMM (bf16 G) + recurrence
    k_gemm_gT_h<<<782, 512, 0, stream>>>(shi, wpih0_hi, wpih0_lo, bp0, bufG, NND);
    k_lstm<<<NB / SB, 512, 0, stream>>>(bufG, wphh0_hi, shi,
                                        nullptr, nullptr, nullptr);

    // ---- LSTM layer 1: 8-wave 2-term gate GEMM (bf16 G) + recurrence + fused FC
    k_gemm_gT_h<<<782, 512, 0, stream>>>(shi, wpih1_hi, wpih1_lo, bp1, bufG, NND);
    k_lstm<<<NB / SB, 512, 0, stream>>>(bufG, wphh1_hi, nullptr,
                                        fcw, fcb, out);
}

// Round 19
// 453.234 us; speedup vs baseline: 1.0157x; 1.0157x over previous
//
#include <hip/hip_runtime.h>

// Problem constants (fixed by the reference file)
#define NND 50000   // nodes
#define NE  600000  // edges
#define TSEQ 50     // sequence length
#define NB  1000    // batch = NND/TSEQ
#define SB  4       // sequences per LSTM workgroup
#define AHS 136     // LDS h-row stride in shorts (128 + 8 pad, 16B-aligned)
#define NSCB 196    // scan blocks: ceil(NND/256)

typedef __attribute__((ext_vector_type(4))) float f32x4;
typedef __attribute__((ext_vector_type(8))) short s16x8;

// ---------------------------------------------------------------- helpers
// Fast activations: raw v_rcp_f32 (~1 ulp); error 3 orders below the proven
// absmax-free bf16 noise floor (R11-R17).
__device__ __forceinline__ float sigf(float x) {
    return __builtin_amdgcn_rcpf(1.0f + __expf(-x));
}
__device__ __forceinline__ float tanhfast(float x) {
    x = fminf(fmaxf(x, -15.f), 15.f);
    float e = __expf(2.f * x);
    return (e - 1.f) * __builtin_amdgcn_rcpf(e + 1.f);
}
// bf16 bit helpers (round-to-nearest-even)
__device__ __forceinline__ unsigned short f2bf(float f) {
    unsigned int u = __float_as_uint(f);
    u = u + 0x7FFFu + ((u >> 16) & 1u);
    return (unsigned short)(u >> 16);
}
__device__ __forceinline__ float bf2f(unsigned short h) {
    return __uint_as_float(((unsigned int)h) << 16);
}
// LDS-only barrier: waits DS ops (lgkmcnt) but leaves GLOBAL ops in flight.
__device__ __forceinline__ void barrier_lds_only() {
    asm volatile("s_waitcnt lgkmcnt(0)\n\ts_barrier" ::: "memory");
}
// G row permutation: node n -> block-local row (blk*200 + step*4 + seq_in_blk).
__device__ __forceinline__ int grow_perm(int n) {
    int grp = n / 200;
    int rem = n % 200;
    return grp * 200 + (n % 50) * 4 + rem / 50;
}

// ---------------------------------------------------------------- CSR build
__global__ void k_count(const int* __restrict__ ei, int* __restrict__ cnt) {
    int e = blockIdx.x * 256 + threadIdx.x;
    if (e < NE) atomicAdd(&cnt[ei[NE + e]], 1);
}

// ---- 3-stage multi-block exclusive scan of cnt -> rowstart (+ fused dinv)
__global__ __launch_bounds__(256) void k_bsum(const int* __restrict__ cnt,
                                              int* __restrict__ bsum) {
    __shared__ int red[256];
    int t = threadIdx.x;
    int idx = blockIdx.x * 256 + t;
    red[t] = (idx < NND) ? cnt[idx] : 0;
    __syncthreads();
    for (int off = 128; off > 0; off >>= 1) {
        if (t < off) red[t] += red[t + off];
        __syncthreads();
    }
    if (t == 0) bsum[blockIdx.x] = red[0];
}

__global__ __launch_bounds__(256) void k_bscan(int* __restrict__ bsum) {
    __shared__ int ps[256];
    int t = threadIdx.x;
    int v = (t < NSCB) ? bsum[t] : 0;
    ps[t] = v;
    __syncthreads();
    for (int off = 1; off < 256; off <<= 1) {
        int u = 0;
        if (t >= off) u = ps[t - off];
        __syncthreads();
        if (t >= off) ps[t] += u;
        __syncthreads();
    }
    if (t < NSCB) bsum[t] = ps[t] - v;   // exclusive
}

__global__ __launch_bounds__(256) void k_bout(const int* __restrict__ cnt,
                                              const int* __restrict__ bsum,
                                              int* __restrict__ rowstart,
                                              float* __restrict__ dinv) {
    __shared__ int ps[256];
    int t = threadIdx.x;
    int idx = blockIdx.x * 256 + t;
    int v = (idx < NND) ? cnt[idx] : 0;
    ps[t] = v;
    __syncthreads();
    for (int off = 1; off < 256; off <<= 1) {
        int u = 0;
        if (t >= off) u = ps[t - off];
        __syncthreads();
        if (t >= off) ps[t] += u;
        __syncthreads();
    }
    int boff = bsum[blockIdx.x];
    if (idx < NND) {
        rowstart[idx] = boff + ps[t] - v;   // exclusive
        dinv[idx] = 1.0f / sqrtf((float)v + 1.0f);   // fused (was k_dinv)
    }
    if (idx == NND - 1) rowstart[NND] = boff + ps[t];  // == NE
}

__global__ void k_fill(const int* __restrict__ ei, const int* __restrict__ rowstart,
                       int* __restrict__ cursor, int* __restrict__ adj) {
    int e = blockIdx.x * 256 + threadIdx.x;
    if (e >= NE) return;
    int s = ei[e], d = ei[NE + e];
    int pos = atomicAdd(&cursor[d], 1);
    adj[rowstart[d] + pos] = s;
}

// ---------------------------------------------------------------- MFMA GEMM
// 2-term GCN GEMM: A plain bf16 (hi only), B split hi/lo. BF16 h output.
__global__ __launch_bounds__(256) void k_gemm_mfma_h2(
    const unsigned short* __restrict__ Ahi,
    const unsigned short* __restrict__ Bhi, const unsigned short* __restrict__ Blo,
    const float* __restrict__ bias, unsigned short* __restrict__ C,
    int M, int Nc, int NT)
{
    __shared__ unsigned short As_hi[128][136];

    const int tid  = threadIdx.x;
    const int lane = tid & 63, wave = tid >> 6;
    const int mw = wave & 1, nw = wave >> 1;
    const int l15 = lane & 15, quad = lane >> 4;
    const int rowBase = blockIdx.y * 128;

    {
        int r0 = tid >> 4;            // 0..15
        int ko = (tid & 15) * 8;      // 0..120
        #pragma unroll
        for (int i = 0; i < 8; ++i) {
            int row = r0 + i * 16;
            int g = rowBase + row;
            uint4 vh = make_uint4(0, 0, 0, 0);
            if (g < M) vh = *(const uint4*)&Ahi[(size_t)g * 128 + ko];
            *(uint4*)&As_hi[row][ko] = vh;
        }
    }
    __syncthreads();

    for (int nt = 0; nt < NT; ++nt) {
        const int colBase = (blockIdx.x * NT + nt) * 64;

        s16x8 bh[2][4], bl[2][4];   // [ns][kq]
        #pragma unroll
        for (int ns = 0; ns < 2; ++ns) {
            int gn = colBase + nw * 32 + ns * 16 + l15;
            #pragma unroll
            for (int kq = 0; kq < 4; ++kq) {
                bh[ns][kq] = *(const s16x8*)&Bhi[(size_t)gn * 128 + kq * 32 + quad * 8];
                bl[ns][kq] = *(const s16x8*)&Blo[(size_t)gn * 128 + kq * 32 + quad * 8];
            }
        }

        f32x4 acc[4][2] = {};
        #pragma unroll
        for (int kq = 0; kq < 4; ++kq) {
            int kof = kq * 32 + quad * 8;
            s16x8 ah[4];
            #pragma unroll
            for (int ms = 0; ms < 4; ++ms) {
                int r = mw * 64 + ms * 16 + l15;
                ah[ms] = *(const s16x8*)&As_hi[r][kof];
            }
            #pragma unroll
            for (int ms = 0; ms < 4; ++ms)
                #pragma unroll
                for (int ns = 0; ns < 2; ++ns)
                    acc[ms][ns] = __builtin_amdgcn_mfma_f32_16x16x32_bf16(ah[ms], bh[ns][kq], acc[ms][ns], 0, 0, 0);
            #pragma unroll
            for (int ms = 0; ms < 4; ++ms)
                #pragma unroll
                for (int ns = 0; ns < 2; ++ns)
                    acc[ms][ns] = __builtin_amdgcn_mfma_f32_16x16x32_bf16(ah[ms], bl[ns][kq], acc[ms][ns], 0, 0, 0);
        }

        #pragma unroll
        for (int ns = 0; ns < 2; ++ns) {
            int col = colBase + nw * 32 + ns * 16 + l15;
            float bv = bias ? bias[col] : 0.f;
            #pragma unroll
            for (int ms = 0; ms < 4; ++ms) {
                int row0 = rowBase + mw * 64 + ms * 16 + quad * 4;
                #pragma unroll
                for (int r = 0; r < 4; ++r) {
                    int row = row0 + r;
                    if (row < M) C[(size_t)row * Nc + col] = f2bf(acc[ms][ns][r] + bv);
                }
            }
        }
    }
}

// Variant: A is raw fp32 (input x); split-bf16 conversion fused into staging.
// BF16 h output.
__global__ __launch_bounds__(256) void k_gemm_mfma_xa(
    const float* __restrict__ X,
    const unsigned short* __restrict__ Bhi, const unsigned short* __restrict__ Blo,
    const float* __restrict__ bias, unsigned short* __restrict__ C,
    int M, int Nc, int NT)
{
    __shared__ unsigned short As_hi[128][136];
    __shared__ unsigned short As_lo[128][136];

    const int tid  = threadIdx.x;
    const int lane = tid & 63, wave = tid >> 6;
    const int mw = wave & 1, nw = wave >> 1;
    const int l15 = lane & 15, quad = lane >> 4;
    const int rowBase = blockIdx.y * 128;

    {
        int r0 = tid >> 4;
        int ko = (tid & 15) * 8;
        #pragma unroll
        for (int i = 0; i < 8; ++i) {
            int row = r0 + i * 16;
            int g = rowBase + row;
            unsigned short hx[8], lx[8];
            if (g < M) {
                float4 v0 = *(const float4*)&X[(size_t)g * 128 + ko];
                float4 v1 = *(const float4*)&X[(size_t)g * 128 + ko + 4];
                const float vv[8] = {v0.x, v0.y, v0.z, v0.w, v1.x, v1.y, v1.z, v1.w};
                #pragma unroll
                for (int e = 0; e < 8; ++e) {
                    hx[e] = f2bf(vv[e]);
                    lx[e] = f2bf(vv[e] - bf2f(hx[e]));
                }
            } else {
                #pragma unroll
                for (int e = 0; e < 8; ++e) { hx[e] = 0; lx[e] = 0; }
            }
            *(uint4*)&As_hi[row][ko] = *(const uint4*)hx;
            *(uint4*)&As_lo[row][ko] = *(const uint4*)lx;
        }
    }
    __syncthreads();

    for (int nt = 0; nt < NT; ++nt) {
        const int colBase = (blockIdx.x * NT + nt) * 64;

        s16x8 bh[2][4], bl[2][4];
        #pragma unroll
        for (int ns = 0; ns < 2; ++ns) {
            int gn = colBase + nw * 32 + ns * 16 + l15;
            #pragma unroll
            for (int kq = 0; kq < 4; ++kq) {
                bh[ns][kq] = *(const s16x8*)&Bhi[(size_t)gn * 128 + kq * 32 + quad * 8];
                bl[ns][kq] = *(const s16x8*)&Blo[(size_t)gn * 128 + kq * 32 + quad * 8];
            }
        }

        f32x4 acc[4][2] = {};
        #pragma unroll
        for (int kq = 0; kq < 4; ++kq) {
            int kof = kq * 32 + quad * 8;
            s16x8 ah[4], al[4];
            #pragma unroll
            for (int ms = 0; ms < 4; ++ms) {
                int r = mw * 64 + ms * 16 + l15;
                ah[ms] = *(const s16x8*)&As_hi[r][kof];
                al[ms] = *(const s16x8*)&As_lo[r][kof];
            }
            #pragma unroll
            for (int ms = 0; ms < 4; ++ms)
                #pragma unroll
                for (int ns = 0; ns < 2; ++ns)
                    acc[ms][ns] = __builtin_amdgcn_mfma_f32_16x16x32_bf16(ah[ms], bh[ns][kq], acc[ms][ns], 0, 0, 0);
            #pragma unroll
            for (int ms = 0; ms < 4; ++ms)
                #pragma unroll
                for (int ns = 0; ns < 2; ++ns)
                    acc[ms][ns] = __builtin_amdgcn_mfma_f32_16x16x32_bf16(al[ms], bh[ns][kq], acc[ms][ns], 0, 0, 0);
            #pragma unroll
            for (int ms = 0; ms < 4; ++ms)
                #pragma unroll
                for (int ns = 0; ns < 2; ++ns)
                    acc[ms][ns] = __builtin_amdgcn_mfma_f32_16x16x32_bf16(ah[ms], bl[ns][kq], acc[ms][ns], 0, 0, 0);
        }

        #pragma unroll
        for (int ns = 0; ns < 2; ++ns) {
            int col = colBase + nw * 32 + ns * 16 + l15;
            float bv = bias ? bias[col] : 0.f;
            #pragma unroll
            for (int ms = 0; ms < 4; ++ms) {
                int row0 = rowBase + mw * 64 + ms * 16 + quad * 4;
                #pragma unroll
                for (int r = 0; r < 4; ++r) {
                    int row = row0 + r;
                    if (row < M) C[(size_t)row * Nc + col] = f2bf(acc[ms][ns][r] + bv);
                }
            }
        }
    }
}

// ---------------------------------------------------------------- gate GEMM v9
// (verified R17, 47.9us) 2-term swapped-operand (R7) + permuted bf16 G
// (R10/R12) + register-pipelined W loads (R15). R18's 8-wave variant
// REGRESSED (53.2us): the limit is the unified VGPR+AGPR file, not wave
// count — reverted.
__global__ __launch_bounds__(256, 1) void k_gemm_gT_h(
    const unsigned short* __restrict__ Ahi,
    const unsigned short* __restrict__ Whi, const unsigned short* __restrict__ Wlo,
    const float* __restrict__ bp, unsigned short* __restrict__ G,
    int M)
{
    __shared__ unsigned short As_hi[64][136];

    const int tid  = threadIdx.x;
    const int lane = tid & 63, wave = tid >> 6;
    const int l15 = lane & 15, quad = lane >> 4;
    const int rowBase = blockIdx.x * 64;

    {
        int r0 = tid >> 4;
        int ko = (tid & 15) * 8;
        #pragma unroll
        for (int i = 0; i < 4; ++i) {
            int row = r0 + i * 16;
            int g = rowBase + row;
            uint4 vh = make_uint4(0, 0, 0, 0);
            if (g < M) vh = *(const uint4*)&Ahi[(size_t)g * 128 + ko];
            *(uint4*)&As_hi[row][ko] = vh;
        }
    }
    __syncthreads();

    const int pb = wave * 128;

    // double-buffered W fragments (tp even -> A, odd -> B)
    s16x8 whA[2][4], wlA[2][4], whB[2][4], wlB[2][4];
    #pragma unroll
    for (int t = 0; t < 2; ++t)
        #pragma unroll
        for (int kq = 0; kq < 4; ++kq) {
            const size_t wrow = (size_t)(pb + t * 16 + l15) * 128 + kq * 32 + quad * 8;
            whA[t][kq] = *(const s16x8*)&Whi[wrow];
            wlA[t][kq] = *(const s16x8*)&Wlo[wrow];
        }

    #pragma unroll
    for (int tp = 0; tp < 4; ++tp) {
        const int p0 = pb + tp * 32;
        s16x8 (&wh)[2][4] = (tp & 1) ? whB : whA;
        s16x8 (&wl)[2][4] = (tp & 1) ? wlB : wlA;
        s16x8 (&whn)[2][4] = (tp & 1) ? whA : whB;
        s16x8 (&wln)[2][4] = (tp & 1) ? wlA : wlB;

        // prefetch NEXT tp's W frags (overlaps this tp's LDS reads + MFMAs)
        if (tp < 3) {
            const int pn = pb + (tp + 1) * 32;
            #pragma unroll
            for (int t = 0; t < 2; ++t)
                #pragma unroll
                for (int kq = 0; kq < 4; ++kq) {
                    const size_t wrow = (size_t)(pn + t * 16 + l15) * 128 + kq * 32 + quad * 8;
                    whn[t][kq] = *(const s16x8*)&Whi[wrow];
                    wln[t][kq] = *(const s16x8*)&Wlo[wrow];
                }
        }

        float4 bv[2];
        #pragma unroll
        for (int t = 0; t < 2; ++t)
            bv[t] = *(const float4*)&bp[p0 + t * 16 + quad * 4];

        #pragma unroll
        for (int rg = 0; rg < 4; ++rg) {
            s16x8 xh[4];
            #pragma unroll
            for (int kq = 0; kq < 4; ++kq)
                xh[kq] = *(const s16x8*)&As_hi[rg * 16 + l15][kq * 32 + quad * 8];
            f32x4 acc[2] = {};
            #pragma unroll
            for (int kq = 0; kq < 4; ++kq)
                #pragma unroll
                for (int t = 0; t < 2; ++t) {
                    acc[t] = __builtin_amdgcn_mfma_f32_16x16x32_bf16(wh[t][kq], xh[kq], acc[t], 0, 0, 0);
                    acc[t] = __builtin_amdgcn_mfma_f32_16x16x32_bf16(wl[t][kq], xh[kq], acc[t], 0, 0, 0);
                }
            const int row = rowBase + rg * 16 + l15;
            if (row < M) {
                const size_t prow = (size_t)grow_perm(row);
                #pragma unroll
                for (int t = 0; t < 2; ++t) {
                    ushort4 o;
                    o.x = f2bf(acc[t][0] + bv[t].x);
                    o.y = f2bf(acc[t][1] + bv[t].y);
                    o.z = f2bf(acc[t][2] + bv[t].z);
                    o.w = f2bf(acc[t][3] + bv[t].w);
                    *(ushort4*)&G[prow * 512 + p0 + t * 16 + quad * 4] = o;
                }
            }
        }
    }
}

// ---------------------------------------------------------------- GCN gather
// h input BF16 (ushort2 per lane per edge). Edge loop unrolled x4;
// accumulation order preserved.
__global__ __launch_bounds__(256) void k_gather(
    const int* __restrict__ rowstart, const int* __restrict__ adj,
    const unsigned short* __restrict__ h, const float* __restrict__ dinv,
    const float* __restrict__ bias,
    unsigned short* __restrict__ hi)
{
    const int n    = blockIdx.x * 4 + (threadIdx.x >> 6);   // grid exactly NND/4
    const int lane = threadIdx.x & 63;
    const int r0 = rowstart[n], r1 = rowstart[n + 1];
    const float dn = dinv[n];

    ushort2 hv = *(const ushort2*)&h[(size_t)n * 128 + 2 * lane];
    float2 acc;
    acc.x = bf2f(hv.x) * dn;
    acc.y = bf2f(hv.y) * dn;

    int i = r0;
    for (; i + 4 <= r1; i += 4) {
        int s0 = adj[i], s1 = adj[i + 1], s2 = adj[i + 2], s3 = adj[i + 3];
        float d0 = dinv[s0], d1 = dinv[s1], d2 = dinv[s2], d3 = dinv[s3];
        ushort2 v0 = *(const ushort2*)&h[(size_t)s0 * 128 + 2 * lane];
        ushort2 v1 = *(const ushort2*)&h[(size_t)s1 * 128 + 2 * lane];
        ushort2 v2 = *(const ushort2*)&h[(size_t)s2 * 128 + 2 * lane];
        ushort2 v3 = *(const ushort2*)&h[(size_t)s3 * 128 + 2 * lane];
        acc.x += bf2f(v0.x) * d0; acc.y += bf2f(v0.y) * d0;
        acc.x += bf2f(v1.x) * d1; acc.y += bf2f(v1.y) * d1;
        acc.x += bf2f(v2.x) * d2; acc.y += bf2f(v2.y) * d2;
        acc.x += bf2f(v3.x) * d3; acc.y += bf2f(v3.y) * d3;
    }
    for (; i < r1; ++i) {
        int s = adj[i];
        float ds = dinv[s];
        ushort2 v = *(const ushort2*)&h[(size_t)s * 128 + 2 * lane];
        acc.x += bf2f(v.x) * ds;
        acc.y += bf2f(v.y) * ds;
    }

    float2 bb = *(const float2*)&bias[2 * lane];
    float vx = fmaxf(acc.x * dn + bb.x, 0.f);
    float vy = fmaxf(acc.y * dn + bb.y, 0.f);
    ushort2 ho;
    ho.x = f2bf(vx);
    ho.y = f2bf(vy);
    *(ushort2*)&hi[(size_t)n * 128 + 2 * lane] = ho;
}

// ---------------------------------------------------------------- prep kernels
__global__ void k_prep_gcnw2(const float* __restrict__ W1, const float* __restrict__ W2,
                             unsigned short* __restrict__ hi1, unsigned short* __restrict__ lo1,
                             unsigned short* __restrict__ hi2, unsigned short* __restrict__ lo2) {
    int t = blockIdx.x * 256 + threadIdx.x;   // grid 128 -> 32768 threads
    const float* W = (t < 16384) ? W1 : W2;
    unsigned short* hi = (t < 16384) ? hi1 : hi2;
    unsigned short* lo = (t < 16384) ? lo1 : lo2;
    int tt = t & 16383;
    int k = tt >> 7, n = tt & 127;
    float v = W[tt];
    unsigned short h = f2bf(v);
    hi[n * 128 + k] = h;
    lo[n * 128 + k] = f2bf(v - bf2f(h));
}

// LSTM prep: w_ih and w_hh [512(r=g*128+j)][128(k)] -> packed-transposed
// split-bf16 wT[p=j*4+g][k]; bias -> bp[p] = b_ih + b_hh.
__global__ void k_prep_lstm(const float* __restrict__ w_ih, const float* __restrict__ w_hh,
                            const float* __restrict__ b_ih, const float* __restrict__ b_hh,
                            unsigned short* __restrict__ ih_hi, unsigned short* __restrict__ ih_lo,
                            unsigned short* __restrict__ hh_hi, unsigned short* __restrict__ hh_lo,
                            float* __restrict__ bp)
{
    int t = blockIdx.x * 256 + threadIdx.x;
    if (t < 65536) {
        int r = t >> 7, k = t & 127;
        int g = r >> 7, j = r & 127;
        int p = (j << 2) + g;
        float v = w_ih[t];
        unsigned short h = f2bf(v);
        ih_hi[p * 128 + k] = h;
        ih_lo[p * 128 + k] = f2bf(v - bf2f(h));
    } else if (t < 131072) {
        int t2 = t - 65536;
        int r = t2 >> 7, k = t2 & 127;
        int g = r >> 7, j = r & 127;
        int p = (j << 2) + g;
        float v = w_hh[t2];
        unsigned short h = f2bf(v);
        hh_hi[p * 128 + k] = h;
        hh_lo[p * 128 + k] = f2bf(v - bf2f(h));
    } else if (t < 131584) {
        int r = t - 131072;   // 0..511
        int g = r >> 7, j = r & 127;
        bp[(j << 2) + g] = b_ih[r] + b_hh[r];
    }
}

// ---------------------------------------------------------------- LSTM recurrence
// v16 (verified R17): 1-term recurrence + bf16 G + LDS-only barrier + fast-rcp
// activations + bumped Hhi pointer + one-step G prefetch.
__global__ __launch_bounds__(512, 2) void k_lstm(
    const unsigned short* __restrict__ G,   // bf16, permuted: [blk][step][4 seq][512]
    const unsigned short* __restrict__ Whi, // 512 x 128, packed-transposed hi
    unsigned short* __restrict__ Hhi,       // (NB*TSEQ) x 128 bf16-hi, or nullptr
    const float* __restrict__ fcw,          // fused FC weight (layer 1) or nullptr
    const float* __restrict__ fcb,
    float* __restrict__ outp)               // NB x 1 output (layer 1) or nullptr
{
    const int tid  = threadIdx.x;
    const int lane = tid & 63, wave = tid >> 6;   // 8 waves
    const int l15  = lane & 15, quad = lane >> 4;
    const int b0   = blockIdx.x * SB;

    __shared__ __align__(16) unsigned short Ah[16 * AHS];  // h bf16 (rows SB..15 zero)
    __shared__ float partw[8][4][72];        // per-wave P patch [wave][b][col in wave]

    // weight fragments: wave owns n-tiles nt0..nt0+3 (n = p = j*4+gate)
    const int nt0 = wave * 4;
    s16x8 bh[4][4];   // [nt][ks]
    #pragma unroll
    for (int nt = 0; nt < 4; ++nt) {
        int p = (nt0 + nt) * 16 + l15;
        #pragma unroll
        for (int ks = 0; ks < 4; ++ks)
            bh[nt][ks] = *(const s16x8*)&Whi[(size_t)p * 128 + ks * 32 + quad * 8];
    }

    for (int i = tid; i < 16 * AHS; i += 512) Ah[i] = 0;

    // phase-2 mapping: lane l of wave w -> (b2, j) with j owned by wave w
    const int b2 = lane >> 4;              // 0..3
    const int jj = wave * 16 + l15;        // hidden unit this lane updates
    const int bg = b0 + b2;                // sequence index (NB % SB == 0)
    float c = 0.f;
    float hn_last = 0.f;

    // permuted-G base: row' = blk*200 + step*4 + b2; step stride = 2048 ushorts
    const unsigned short* gb = &G[((size_t)blockIdx.x * 200 + b2) * 512 + (jj << 2)];
    ushort4 gr_cur = *(const ushort4*)&gb[0];
    // hoisted Hhi pointer (bumped by 128 shorts per step)
    unsigned short* hptr = Hhi ? &Hhi[(size_t)bg * TSEQ * 128 + jj] : nullptr;

    __syncthreads();

    for (int step = 0; step < TSEQ; ++step) {
        // prefetch NEXT step's gate input (full step of latency cover;
        // NOT drained by the lds-only barrier below)
        const int nstep = (step + 1 < TSEQ) ? step + 1 : step;
        const ushort4 gr_nxt = *(const ushort4*)&gb[(size_t)nstep * 2048];

        // phase 1: MFMA  P = bf16(h) @ bf16(Whh)  (1-term)
        f32x4 acc[4] = {};
        #pragma unroll
        for (int ks = 0; ks < 4; ++ks) {
            s16x8 ah = *(const s16x8*)&Ah[l15 * AHS + ks * 32 + quad * 8];
            #pragma unroll
            for (int nt = 0; nt < 4; ++nt)
                acc[nt] = __builtin_amdgcn_mfma_f32_16x16x32_bf16(ah, bh[nt][ks], acc[nt], 0, 0, 0);
        }

        // intra-wave exchange: quad-0 lanes hold rows 0..3 (the real seqs)
        if (quad == 0) {
            #pragma unroll
            for (int nt = 0; nt < 4; ++nt)
                #pragma unroll
                for (int r = 0; r < 4; ++r)
                    partw[wave][r][nt * 16 + l15] = acc[nt][r];
        }
        // same-wave producer/consumer: compiler inserts lgkmcnt wait, no barrier

        // phase 2: LSTM cell for (b2, jj); reads this wave's own patch
        {
            float4 pa = *(const float4*)&partw[wave][b2][l15 * 4];
            float xi = pa.x + bf2f(gr_cur.x);
            float xf = pa.y + bf2f(gr_cur.y);
            float xg = pa.z + bf2f(gr_cur.z);
            float xo = pa.w + bf2f(gr_cur.w);
            float ii = sigf(xi), ff = sigf(xf), gg = tanhfast(xg), oo = sigf(xo);
            float cn = ff * c + ii * gg;
            c = cn;
            float hn = oo * tanhfast(cn);
            hn_last = hn;
            unsigned short hh = f2bf(hn);
            Ah[b2 * AHS + jj] = hh;
            if (hptr) {
                *hptr = hh;
                hptr += 128;
            }
        }
        gr_cur = gr_nxt;
        // LDS-only barrier: Ah writes visible to all waves; globals in flight
        barrier_lds_only();
    }

    // fused FC head (layer 1): out[bg] = dot(h_last[bg], fcw) + fcb
    if (outp) {
        float* red = (float*)Ah;   // 2 KiB scratch, Ah is dead now
        red[b2 * 128 + jj] = hn_last * fcw[jj];
        __syncthreads();
        if (wave < 4) {            // wave w reduces sequence b0+w
            float v = red[wave * 128 + lane] + red[wave * 128 + lane + 64];
            #pragma unroll
            for (int off = 32; off > 0; off >>= 1)
                v += __shfl_down(v, off);
            if (lane == 0) outp[b0 + wave] = v + fcb[0];
        }
    }
}

// ---------------------------------------------------------------- launch
extern "C" void kernel_launch(void* const* d_in, const int* in_sizes, int n_in,
                              void* d_out, int out_size, void* d_ws, size_t ws_size,
                              hipStream_t stream)
{
    const float* x    = (const float*)d_in[0];
    const int*   ei   = (const int*)d_in[1];
    const float* W1   = (const float*)d_in[3];
    const float* b1   = (const float*)d_in[4];
    const float* W2   = (const float*)d_in[5];
    const float* b2   = (const float*)d_in[6];
    const float* fcw  = (const float*)d_in[7];
    const float* fcb  = (const float*)d_in[8];
    const float* wih0 = (const float*)d_in[9];
    const float* whh0 = (const float*)d_in[10];
    const float* bih0 = (const float*)d_in[11];
    const float* bhh0 = (const float*)d_in[12];
    const float* wih1 = (const float*)d_in[13];
    const float* whh1 = (const float*)d_in[14];
    const float* bih1 = (const float*)d_in[15];
    const float* bhh1 = (const float*)d_in[16];
    float* out = (float*)d_out;

    char* ws = (char*)d_ws;
    // ---- persistent regions
    unsigned short* shi = (unsigned short*)(ws + 0);          // 12.8 MB
    unsigned short* bufG = (unsigned short*)(ws + 51200000);  // 51.2 MB bf16 (ends 102.4M)

    // ---- GCN-phase regions (overlap bufG region; dead before gate GEMM writes)
    unsigned short* xhi = (unsigned short*)(ws + 51200000);   // 12.8 MB
    unsigned short* bufHg = (unsigned short*)(ws + 76800000); // 12.8 MB bf16 h
    int* cnt      = (int*)(ws + 102400000);                   // 200000 B (pad 204800)
    int* cursor   = (int*)(ws + 102604800);                   // contiguous with cnt
    int* rowstart = (int*)(ws + 102809600);
    int* adj      = (int*)(ws + 103014400);                   // 2.4 MB (ends 105.42M)
    int* bsum     = (int*)(ws + 105420800);                   // NSCB ints

    float* dinv = (float*)(ws + 153600000);
    float* bp0  = (float*)(ws + 153800192);
    float* bp1  = (float*)(ws + 153802240);
    unsigned short* w1t_hi   = (unsigned short*)(ws + 153804288);
    unsigned short* w1t_lo   = (unsigned short*)(ws + 153837056);
    unsigned short* w2t_hi   = (unsigned short*)(ws + 153869824);
    unsigned short* w2t_lo   = (unsigned short*)(ws + 153902592);
    unsigned short* wpih0_hi = (unsigned short*)(ws + 153935360);
    unsigned short* wpih0_lo = (unsigned short*)(ws + 154066432);
    unsigned short* wpih1_hi = (unsigned short*)(ws + 154197504);
    unsigned short* wpih1_lo = (unsigned short*)(ws + 154328576);
    unsigned short* wphh0_hi = (unsigned short*)(ws + 154459648);
    unsigned short* wphh0_lo = (unsigned short*)(ws + 154590720);
    unsigned short* wphh1_hi = (unsigned short*)(ws + 154721792);
    unsigned short* wphh1_lo = (unsigned short*)(ws + 154852864);

    // ---- CSR build + dinv (multi-block scan); cnt+cursor zeroed in ONE memset
    hipMemsetAsync(cnt, 0, 409600, stream);
    k_count<<<(NE + 255) / 256, 256, 0, stream>>>(ei, cnt);
    k_bsum<<<NSCB, 256, 0, stream>>>(cnt, bsum);
    k_bscan<<<1, 256, 0, stream>>>(bsum);
    k_bout<<<NSCB, 256, 0, stream>>>(cnt, bsum, rowstart, dinv);
    k_fill<<<(NE + 255) / 256, 256, 0, stream>>>(ei, rowstart, cursor, adj);

    // ---- weight prep
    k_prep_gcnw2<<<128, 256, 0, stream>>>(W1, W2, w1t_hi, w1t_lo, w2t_hi, w2t_lo);
    k_prep_lstm<<<514, 256, 0, stream>>>(wih0, whh0, bih0, bhh0,
                                         wpih0_hi, wpih0_lo, wphh0_hi, wphh0_lo, bp0);
    k_prep_lstm<<<514, 256, 0, stream>>>(wih1, whh1, bih1, bhh1,
                                         wpih1_hi, wpih1_lo, wphh1_hi, wphh1_lo, bp1);

    dim3 gH(1, 391);     // GCN GEMMs: 128-row panel, NT=2 (128 cols)

    // ---- GCN layer 1 (fp32 A, convert-on-stage, split precision; bf16 h out)
    k_gemm_mfma_xa<<<gH, 256, 0, stream>>>(x, w1t_hi, w1t_lo, nullptr, bufHg, NND, 128, 2);
    k_gather<<<NND / 4, 256, 0, stream>>>(rowstart, adj, bufHg, dinv, b1, xhi);

    // ---- GCN layer 2 (2-term: A = bf16 hi only; bf16 h out)
    k_gemm_mfma_h2<<<gH, 256, 0, stream>>>(xhi, w2t_hi, w2t_lo, nullptr, bufHg, NND, 128, 2);
    k_gather<<<NND / 4, 256, 0, stream>>>(rowstart, adj, bufHg, dinv, b2, shi);

    // ---- LSTM layer 0: 2-term gate GEMM (bf16 G) + recurrence (H -> shi in-place)
    k_gemm_gT_h<<<782, 256, 0, stream>>>(shi, wpih0_hi, wpih0_lo, bp0, bufG, NND);
    k_lstm<<<NB / SB, 512, 0, stream>>>(bufG, wphh0_hi, shi,
                                        nullptr, nullptr, nullptr);

    // ---- LSTM layer 1: 2-term gate GEMM (bf16 G) + recurrence + fused FC
    k_gemm_gT_h<<<782, 256, 0, stream>>>(shi, wpih1_hi, wpih1_lo, bp1, bufG, NND);
    k_lstm<<<NB / SB, 512, 0, stream>>>(bufG, wphh1_hi, nullptr,
                                        fcw, fcb, out);
}

// Round 20
// 415.622 us; speedup vs baseline: 1.1076x; 1.0905x over previous
//
#include <hip/hip_runtime.h>

// Problem constants (fixed by the reference file)
#define NND 50000   // nodes
#define NE  600000  // edges
#define TSEQ 50     // sequence length
#define NB  1000    // batch = NND/TSEQ
#define SB  4       // sequences per LSTM workgroup
#define AHS 136     // LDS h-row stride in shorts (128 + 8 pad, 16B-aligned)
#define NSCB 196    // scan blocks: ceil(NND/256)

typedef __attribute__((ext_vector_type(4))) float f32x4;
typedef __attribute__((ext_vector_type(8))) short s16x8;

// ---------------------------------------------------------------- helpers
// Fast activations: raw v_rcp_f32 (~1 ulp); error 3 orders below the proven
// absmax-free bf16 noise floor (R11-R17).
__device__ __forceinline__ float sigf(float x) {
    return __builtin_amdgcn_rcpf(1.0f + __expf(-x));
}
__device__ __forceinline__ float tanhfast(float x) {
    x = fminf(fmaxf(x, -15.f), 15.f);
    float e = __expf(2.f * x);
    return (e - 1.f) * __builtin_amdgcn_rcpf(e + 1.f);
}
// bf16 bit helpers (round-to-nearest-even)
__device__ __forceinline__ unsigned short f2bf(float f) {
    unsigned int u = __float_as_uint(f);
    u = u + 0x7FFFu + ((u >> 16) & 1u);
    return (unsigned short)(u >> 16);
}
__device__ __forceinline__ float bf2f(unsigned short h) {
    return __uint_as_float(((unsigned int)h) << 16);
}
// LDS-only barrier: waits DS ops (lgkmcnt) but leaves GLOBAL ops in flight.
__device__ __forceinline__ void barrier_lds_only() {
    asm volatile("s_waitcnt lgkmcnt(0)\n\ts_barrier" ::: "memory");
}
// G row permutation: node n -> block-local row (blk*200 + step*4 + seq_in_blk).
__device__ __forceinline__ int grow_perm(int n) {
    int grp = n / 200;
    int rem = n % 200;
    return grp * 200 + (n % 50) * 4 + rem / 50;
}

// ---------------------------------------------------------------- CSR build
__global__ void k_count(const int* __restrict__ ei, int* __restrict__ cnt) {
    int e = blockIdx.x * 256 + threadIdx.x;
    if (e < NE) atomicAdd(&cnt[ei[NE + e]], 1);
}

// ---- 3-stage multi-block exclusive scan of cnt -> rowstart (+ fused dinv)
__global__ __launch_bounds__(256) void k_bsum(const int* __restrict__ cnt,
                                              int* __restrict__ bsum) {
    __shared__ int red[256];
    int t = threadIdx.x;
    int idx = blockIdx.x * 256 + t;
    red[t] = (idx < NND) ? cnt[idx] : 0;
    __syncthreads();
    for (int off = 128; off > 0; off >>= 1) {
        if (t < off) red[t] += red[t + off];
        __syncthreads();
    }
    if (t == 0) bsum[blockIdx.x] = red[0];
}

__global__ __launch_bounds__(256) void k_bscan(int* __restrict__ bsum) {
    __shared__ int ps[256];
    int t = threadIdx.x;
    int v = (t < NSCB) ? bsum[t] : 0;
    ps[t] = v;
    __syncthreads();
    for (int off = 1; off < 256; off <<= 1) {
        int u = 0;
        if (t >= off) u = ps[t - off];
        __syncthreads();
        if (t >= off) ps[t] += u;
        __syncthreads();
    }
    if (t < NSCB) bsum[t] = ps[t] - v;   // exclusive
}

__global__ __launch_bounds__(256) void k_bout(const int* __restrict__ cnt,
                                              const int* __restrict__ bsum,
                                              int* __restrict__ rowstart,
                                              float* __restrict__ dinv) {
    __shared__ int ps[256];
    int t = threadIdx.x;
    int idx = blockIdx.x * 256 + t;
    int v = (idx < NND) ? cnt[idx] : 0;
    ps[t] = v;
    __syncthreads();
    for (int off = 1; off < 256; off <<= 1) {
        int u = 0;
        if (t >= off) u = ps[t - off];
        __syncthreads();
        if (t >= off) ps[t] += u;
        __syncthreads();
    }
    int boff = bsum[blockIdx.x];
    if (idx < NND) {
        rowstart[idx] = boff + ps[t] - v;   // exclusive
        dinv[idx] = 1.0f / sqrtf((float)v + 1.0f);   // fused (was k_dinv)
    }
    if (idx == NND - 1) rowstart[NND] = boff + ps[t];  // == NE
}

__global__ void k_fill(const int* __restrict__ ei, const int* __restrict__ rowstart,
                       int* __restrict__ cursor, int* __restrict__ adj) {
    int e = blockIdx.x * 256 + threadIdx.x;
    if (e >= NE) return;
    int s = ei[e], d = ei[NE + e];
    int pos = atomicAdd(&cursor[d], 1);
    adj[rowstart[d] + pos] = s;
}

// ---------------------------------------------------------------- MFMA GEMM
// 2-term GCN GEMM: A plain bf16 (hi only), B split hi/lo. BF16 h output.
__global__ __launch_bounds__(256) void k_gemm_mfma_h2(
    const unsigned short* __restrict__ Ahi,
    const unsigned short* __restrict__ Bhi, const unsigned short* __restrict__ Blo,
    const float* __restrict__ bias, unsigned short* __restrict__ C,
    int M, int Nc, int NT)
{
    __shared__ unsigned short As_hi[128][136];

    const int tid  = threadIdx.x;
    const int lane = tid & 63, wave = tid >> 6;
    const int mw = wave & 1, nw = wave >> 1;
    const int l15 = lane & 15, quad = lane >> 4;
    const int rowBase = blockIdx.y * 128;

    {
        int r0 = tid >> 4;            // 0..15
        int ko = (tid & 15) * 8;      // 0..120
        #pragma unroll
        for (int i = 0; i < 8; ++i) {
            int row = r0 + i * 16;
            int g = rowBase + row;
            uint4 vh = make_uint4(0, 0, 0, 0);
            if (g < M) vh = *(const uint4*)&Ahi[(size_t)g * 128 + ko];
            *(uint4*)&As_hi[row][ko] = vh;
        }
    }
    __syncthreads();

    for (int nt = 0; nt < NT; ++nt) {
        const int colBase = (blockIdx.x * NT + nt) * 64;

        s16x8 bh[2][4], bl[2][4];   // [ns][kq]
        #pragma unroll
        for (int ns = 0; ns < 2; ++ns) {
            int gn = colBase + nw * 32 + ns * 16 + l15;
            #pragma unroll
            for (int kq = 0; kq < 4; ++kq) {
                bh[ns][kq] = *(const s16x8*)&Bhi[(size_t)gn * 128 + kq * 32 + quad * 8];
                bl[ns][kq] = *(const s16x8*)&Blo[(size_t)gn * 128 + kq * 32 + quad * 8];
            }
        }

        f32x4 acc[4][2] = {};
        #pragma unroll
        for (int kq = 0; kq < 4; ++kq) {
            int kof = kq * 32 + quad * 8;
            s16x8 ah[4];
            #pragma unroll
            for (int ms = 0; ms < 4; ++ms) {
                int r = mw * 64 + ms * 16 + l15;
                ah[ms] = *(const s16x8*)&As_hi[r][kof];
            }
            #pragma unroll
            for (int ms = 0; ms < 4; ++ms)
                #pragma unroll
                for (int ns = 0; ns < 2; ++ns)
                    acc[ms][ns] = __builtin_amdgcn_mfma_f32_16x16x32_bf16(ah[ms], bh[ns][kq], acc[ms][ns], 0, 0, 0);
            #pragma unroll
            for (int ms = 0; ms < 4; ++ms)
                #pragma unroll
                for (int ns = 0; ns < 2; ++ns)
                    acc[ms][ns] = __builtin_amdgcn_mfma_f32_16x16x32_bf16(ah[ms], bl[ns][kq], acc[ms][ns], 0, 0, 0);
        }

        #pragma unroll
        for (int ns = 0; ns < 2; ++ns) {
            int col = colBase + nw * 32 + ns * 16 + l15;
            float bv = bias ? bias[col] : 0.f;
            #pragma unroll
            for (int ms = 0; ms < 4; ++ms) {
                int row0 = rowBase + mw * 64 + ms * 16 + quad * 4;
                #pragma unroll
                for (int r = 0; r < 4; ++r) {
                    int row = row0 + r;
                    if (row < M) C[(size_t)row * Nc + col] = f2bf(acc[ms][ns][r] + bv);
                }
            }
        }
    }
}

// Variant: A is raw fp32 (input x); split-bf16 conversion fused into staging.
// BF16 h output.
__global__ __launch_bounds__(256) void k_gemm_mfma_xa(
    const float* __restrict__ X,
    const unsigned short* __restrict__ Bhi, const unsigned short* __restrict__ Blo,
    const float* __restrict__ bias, unsigned short* __restrict__ C,
    int M, int Nc, int NT)
{
    __shared__ unsigned short As_hi[128][136];
    __shared__ unsigned short As_lo[128][136];

    const int tid  = threadIdx.x;
    const int lane = tid & 63, wave = tid >> 6;
    const int mw = wave & 1, nw = wave >> 1;
    const int l15 = lane & 15, quad = lane >> 4;
    const int rowBase = blockIdx.y * 128;

    {
        int r0 = tid >> 4;
        int ko = (tid & 15) * 8;
        #pragma unroll
        for (int i = 0; i < 8; ++i) {
            int row = r0 + i * 16;
            int g = rowBase + row;
            unsigned short hx[8], lx[8];
            if (g < M) {
                float4 v0 = *(const float4*)&X[(size_t)g * 128 + ko];
                float4 v1 = *(const float4*)&X[(size_t)g * 128 + ko + 4];
                const float vv[8] = {v0.x, v0.y, v0.z, v0.w, v1.x, v1.y, v1.z, v1.w};
                #pragma unroll
                for (int e = 0; e < 8; ++e) {
                    hx[e] = f2bf(vv[e]);
                    lx[e] = f2bf(vv[e] - bf2f(hx[e]));
                }
            } else {
                #pragma unroll
                for (int e = 0; e < 8; ++e) { hx[e] = 0; lx[e] = 0; }
            }
            *(uint4*)&As_hi[row][ko] = *(const uint4*)hx;
            *(uint4*)&As_lo[row][ko] = *(const uint4*)lx;
        }
    }
    __syncthreads();

    for (int nt = 0; nt < NT; ++nt) {
        const int colBase = (blockIdx.x * NT + nt) * 64;

        s16x8 bh[2][4], bl[2][4];
        #pragma unroll
        for (int ns = 0; ns < 2; ++ns) {
            int gn = colBase + nw * 32 + ns * 16 + l15;
            #pragma unroll
            for (int kq = 0; kq < 4; ++kq) {
                bh[ns][kq] = *(const s16x8*)&Bhi[(size_t)gn * 128 + kq * 32 + quad * 8];
                bl[ns][kq] = *(const s16x8*)&Blo[(size_t)gn * 128 + kq * 32 + quad * 8];
            }
        }

        f32x4 acc[4][2] = {};
        #pragma unroll
        for (int kq = 0; kq < 4; ++kq) {
            int kof = kq * 32 + quad * 8;
            s16x8 ah[4], al[4];
            #pragma unroll
            for (int ms = 0; ms < 4; ++ms) {
                int r = mw * 64 + ms * 16 + l15;
                ah[ms] = *(const s16x8*)&As_hi[r][kof];
                al[ms] = *(const s16x8*)&As_lo[r][kof];
            }
            #pragma unroll
            for (int ms = 0; ms < 4; ++ms)
                #pragma unroll
                for (int ns = 0; ns < 2; ++ns)
                    acc[ms][ns] = __builtin_amdgcn_mfma_f32_16x16x32_bf16(ah[ms], bh[ns][kq], acc[ms][ns], 0, 0, 0);
            #pragma unroll
            for (int ms = 0; ms < 4; ++ms)
                #pragma unroll
                for (int ns = 0; ns < 2; ++ns)
                    acc[ms][ns] = __builtin_amdgcn_mfma_f32_16x16x32_bf16(al[ms], bh[ns][kq], acc[ms][ns], 0, 0, 0);
            #pragma unroll
            for (int ms = 0; ms < 4; ++ms)
                #pragma unroll
                for (int ns = 0; ns < 2; ++ns)
                    acc[ms][ns] = __builtin_amdgcn_mfma_f32_16x16x32_bf16(ah[ms], bl[ns][kq], acc[ms][ns], 0, 0, 0);
        }

        #pragma unroll
        for (int ns = 0; ns < 2; ++ns) {
            int col = colBase + nw * 32 + ns * 16 + l15;
            float bv = bias ? bias[col] : 0.f;
            #pragma unroll
            for (int ms = 0; ms < 4; ++ms) {
                int row0 = rowBase + mw * 64 + ms * 16 + quad * 4;
                #pragma unroll
                for (int r = 0; r < 4; ++r) {
                    int row = row0 + r;
                    if (row < M) C[(size_t)row * Nc + col] = f2bf(acc[ms][ns][r] + bv);
                }
            }
        }
    }
}

// ---------------------------------------------------------------- gate GEMM v11
// W-AMORTIZED MULTI-PANEL (this round). R17-19 arithmetic: per-block latency
// ~38K cycles vs ~2.5K of MFMA issue — dominated by the per-block W stream
// (256KB through L2 per block, 782 blocks, 3 dispatch rounds). Now: 512 thr /
// 8 waves; each wave owns 64 p-cols with its FULL W slice register-resident
// (128 VGPRs, loaded ONCE); block processes 256 rows = 4 panels of 64 with
// double-buffered LDS A. Grid 196 = one co-resident round, W cost amortized
// 4x. Per-element accumulation order (kq -> hi,lo) unchanged -> bit-identical.
__global__ __launch_bounds__(512, 1) void k_gemm_gT_h(
    const unsigned short* __restrict__ Ahi,
    const unsigned short* __restrict__ Whi, const unsigned short* __restrict__ Wlo,
    const float* __restrict__ bp, unsigned short* __restrict__ G,
    int M)
{
    __shared__ unsigned short As[2][64][136];

    const int tid  = threadIdx.x;
    const int lane = tid & 63, wave = tid >> 6;   // 8 waves
    const int l15 = lane & 15, quad = lane >> 4;
    const int rowBase0 = blockIdx.x * 256;
    const int pb = wave * 64;                     // wave's 64 gate-cols

    // full W slice resident: 4 tiles x 4 kq, hi+lo = 128 VGPRs
    s16x8 wh[4][4], wl[4][4];
    #pragma unroll
    for (int t = 0; t < 4; ++t)
        #pragma unroll
        for (int kq = 0; kq < 4; ++kq) {
            const size_t wrow = (size_t)(pb + t * 16 + l15) * 128 + kq * 32 + quad * 8;
            wh[t][kq] = *(const s16x8*)&Whi[wrow];
            wl[t][kq] = *(const s16x8*)&Wlo[wrow];
        }
    float4 bv[4];
    #pragma unroll
    for (int t = 0; t < 4; ++t)
        bv[t] = *(const float4*)&bp[pb + t * 16 + quad * 4];

    // stage panel 0 (64 rows x 128 shorts; 8 threads/row, 2 x 16B each)
    {
        int r0 = tid >> 3, ko = (tid & 7) * 8;
        int g = rowBase0 + r0;
        uint4 v0 = make_uint4(0, 0, 0, 0), v1 = make_uint4(0, 0, 0, 0);
        if (g < M) {
            v0 = *(const uint4*)&Ahi[(size_t)g * 128 + ko];
            v1 = *(const uint4*)&Ahi[(size_t)g * 128 + ko + 64];
        }
        *(uint4*)&As[0][r0][ko] = v0;
        *(uint4*)&As[0][r0][ko + 64] = v1;
    }
    __syncthreads();

    #pragma unroll
    for (int p = 0; p < 4; ++p) {
        const int cur = p & 1;
        // prefetch next panel into the other buffer (overlaps this panel's MFMAs)
        if (p < 3) {
            int r0 = tid >> 3, ko = (tid & 7) * 8;
            int g = rowBase0 + (p + 1) * 64 + r0;
            uint4 v0 = make_uint4(0, 0, 0, 0), v1 = make_uint4(0, 0, 0, 0);
            if (g < M) {
                v0 = *(const uint4*)&Ahi[(size_t)g * 128 + ko];
                v1 = *(const uint4*)&Ahi[(size_t)g * 128 + ko + 64];
            }
            *(uint4*)&As[cur ^ 1][r0][ko] = v0;
            *(uint4*)&As[cur ^ 1][r0][ko + 64] = v1;
        }

        const int rowBase = rowBase0 + p * 64;
        #pragma unroll
        for (int rg = 0; rg < 4; ++rg) {
            s16x8 xh[4];
            #pragma unroll
            for (int kq = 0; kq < 4; ++kq)
                xh[kq] = *(const s16x8*)&As[cur][rg * 16 + l15][kq * 32 + quad * 8];
            const int row = rowBase + rg * 16 + l15;
            const size_t prow = (row < M) ? (size_t)grow_perm(row) : 0;
            #pragma unroll
            for (int t = 0; t < 4; ++t) {
                f32x4 acc = {};
                #pragma unroll
                for (int kq = 0; kq < 4; ++kq) {
                    acc = __builtin_amdgcn_mfma_f32_16x16x32_bf16(wh[t][kq], xh[kq], acc, 0, 0, 0);
                    acc = __builtin_amdgcn_mfma_f32_16x16x32_bf16(wl[t][kq], xh[kq], acc, 0, 0, 0);
                }
                if (row < M) {
                    ushort4 o;
                    o.x = f2bf(acc[0] + bv[t].x);
                    o.y = f2bf(acc[1] + bv[t].y);
                    o.z = f2bf(acc[2] + bv[t].z);
                    o.w = f2bf(acc[3] + bv[t].w);
                    *(ushort4*)&G[prow * 512 + pb + t * 16 + quad * 4] = o;
                }
            }
        }
        __syncthreads();
    }
}

// ---------------------------------------------------------------- GCN gather
// h input BF16 (ushort2 per lane per edge). Edge loop unrolled x4;
// accumulation order preserved.
__global__ __launch_bounds__(256) void k_gather(
    const int* __restrict__ rowstart, const int* __restrict__ adj,
    const unsigned short* __restrict__ h, const float* __restrict__ dinv,
    const float* __restrict__ bias,
    unsigned short* __restrict__ hi)
{
    const int n    = blockIdx.x * 4 + (threadIdx.x >> 6);   // grid exactly NND/4
    const int lane = threadIdx.x & 63;
    const int r0 = rowstart[n], r1 = rowstart[n + 1];
    const float dn = dinv[n];

    ushort2 hv = *(const ushort2*)&h[(size_t)n * 128 + 2 * lane];
    float2 acc;
    acc.x = bf2f(hv.x) * dn;
    acc.y = bf2f(hv.y) * dn;

    int i = r0;
    for (; i + 4 <= r1; i += 4) {
        int s0 = adj[i], s1 = adj[i + 1], s2 = adj[i + 2], s3 = adj[i + 3];
        float d0 = dinv[s0], d1 = dinv[s1], d2 = dinv[s2], d3 = dinv[s3];
        ushort2 v0 = *(const ushort2*)&h[(size_t)s0 * 128 + 2 * lane];
        ushort2 v1 = *(const ushort2*)&h[(size_t)s1 * 128 + 2 * lane];
        ushort2 v2 = *(const ushort2*)&h[(size_t)s2 * 128 + 2 * lane];
        ushort2 v3 = *(const ushort2*)&h[(size_t)s3 * 128 + 2 * lane];
        acc.x += bf2f(v0.x) * d0; acc.y += bf2f(v0.y) * d0;
        acc.x += bf2f(v1.x) * d1; acc.y += bf2f(v1.y) * d1;
        acc.x += bf2f(v2.x) * d2; acc.y += bf2f(v2.y) * d2;
        acc.x += bf2f(v3.x) * d3; acc.y += bf2f(v3.y) * d3;
    }
    for (; i < r1; ++i) {
        int s = adj[i];
        float ds = dinv[s];
        ushort2 v = *(const ushort2*)&h[(size_t)s * 128 + 2 * lane];
        acc.x += bf2f(v.x) * ds;
        acc.y += bf2f(v.y) * ds;
    }

    float2 bb = *(const float2*)&bias[2 * lane];
    float vx = fmaxf(acc.x * dn + bb.x, 0.f);
    float vy = fmaxf(acc.y * dn + bb.y, 0.f);
    ushort2 ho;
    ho.x = f2bf(vx);
    ho.y = f2bf(vy);
    *(ushort2*)&hi[(size_t)n * 128 + 2 * lane] = ho;
}

// ---------------------------------------------------------------- prep kernels
__global__ void k_prep_gcnw2(const float* __restrict__ W1, const float* __restrict__ W2,
                             unsigned short* __restrict__ hi1, unsigned short* __restrict__ lo1,
                             unsigned short* __restrict__ hi2, unsigned short* __restrict__ lo2) {
    int t = blockIdx.x * 256 + threadIdx.x;   // grid 128 -> 32768 threads
    const float* W = (t < 16384) ? W1 : W2;
    unsigned short* hi = (t < 16384) ? hi1 : hi2;
    unsigned short* lo = (t < 16384) ? lo1 : lo2;
    int tt = t & 16383;
    int k = tt >> 7, n = tt & 127;
    float v = W[tt];
    unsigned short h = f2bf(v);
    hi[n * 128 + k] = h;
    lo[n * 128 + k] = f2bf(v - bf2f(h));
}

// LSTM prep: w_ih and w_hh [512(r=g*128+j)][128(k)] -> packed-transposed
// split-bf16 wT[p=j*4+g][k]; bias -> bp[p] = b_ih + b_hh.
__global__ void k_prep_lstm(const float* __restrict__ w_ih, const float* __restrict__ w_hh,
                            const float* __restrict__ b_ih, const float* __restrict__ b_hh,
                            unsigned short* __restrict__ ih_hi, unsigned short* __restrict__ ih_lo,
                            unsigned short* __restrict__ hh_hi, unsigned short* __restrict__ hh_lo,
                            float* __restrict__ bp)
{
    int t = blockIdx.x * 256 + threadIdx.x;
    if (t < 65536) {
        int r = t >> 7, k = t & 127;
        int g = r >> 7, j = r & 127;
        int p = (j << 2) + g;
        float v = w_ih[t];
        unsigned short h = f2bf(v);
        ih_hi[p * 128 + k] = h;
        ih_lo[p * 128 + k] = f2bf(v - bf2f(h));
    } else if (t < 131072) {
        int t2 = t - 65536;
        int r = t2 >> 7, k = t2 & 127;
        int g = r >> 7, j = r & 127;
        int p = (j << 2) + g;
        float v = w_hh[t2];
        unsigned short h = f2bf(v);
        hh_hi[p * 128 + k] = h;
        hh_lo[p * 128 + k] = f2bf(v - bf2f(h));
    } else if (t < 131584) {
        int r = t - 131072;   // 0..511
        int g = r >> 7, j = r & 127;
        bp[(j << 2) + g] = b_ih[r] + b_hh[r];
    }
}

// ---------------------------------------------------------------- LSTM recurrence
// v16 (verified R17): 1-term recurrence + bf16 G + LDS-only barrier + fast-rcp
// activations + bumped Hhi pointer + one-step G prefetch.
__global__ __launch_bounds__(512, 2) void k_lstm(
    const unsigned short* __restrict__ G,   // bf16, permuted: [blk][step][4 seq][512]
    const unsigned short* __restrict__ Whi, // 512 x 128, packed-transposed hi
    unsigned short* __restrict__ Hhi,       // (NB*TSEQ) x 128 bf16-hi, or nullptr
    const float* __restrict__ fcw,          // fused FC weight (layer 1) or nullptr
    const float* __restrict__ fcb,
    float* __restrict__ outp)               // NB x 1 output (layer 1) or nullptr
{
    const int tid  = threadIdx.x;
    const int lane = tid & 63, wave = tid >> 6;   // 8 waves
    const int l15  = lane & 15, quad = lane >> 4;
    const int b0   = blockIdx.x * SB;

    __shared__ __align__(16) unsigned short Ah[16 * AHS];  // h bf16 (rows SB..15 zero)
    __shared__ float partw[8][4][72];        // per-wave P patch [wave][b][col in wave]

    // weight fragments: wave owns n-tiles nt0..nt0+3 (n = p = j*4+gate)
    const int nt0 = wave * 4;
    s16x8 bh[4][4];   // [nt][ks]
    #pragma unroll
    for (int nt = 0; nt < 4; ++nt) {
        int p = (nt0 + nt) * 16 + l15;
        #pragma unroll
        for (int ks = 0; ks < 4; ++ks)
            bh[nt][ks] = *(const s16x8*)&Whi[(size_t)p * 128 + ks * 32 + quad * 8];
    }

    for (int i = tid; i < 16 * AHS; i += 512) Ah[i] = 0;

    // phase-2 mapping: lane l of wave w -> (b2, j) with j owned by wave w
    const int b2 = lane >> 4;              // 0..3
    const int jj = wave * 16 + l15;        // hidden unit this lane updates
    const int bg = b0 + b2;                // sequence index (NB % SB == 0)
    float c = 0.f;
    float hn_last = 0.f;

    // permuted-G base: row' = blk*200 + step*4 + b2; step stride = 2048 ushorts
    const unsigned short* gb = &G[((size_t)blockIdx.x * 200 + b2) * 512 + (jj << 2)];
    ushort4 gr_cur = *(const ushort4*)&gb[0];
    // hoisted Hhi pointer (bumped by 128 shorts per step)
    unsigned short* hptr = Hhi ? &Hhi[(size_t)bg * TSEQ * 128 + jj] : nullptr;

    __syncthreads();

    for (int step = 0; step < TSEQ; ++step) {
        // prefetch NEXT step's gate input (full step of latency cover;
        // NOT drained by the lds-only barrier below)
        const int nstep = (step + 1 < TSEQ) ? step + 1 : step;
        const ushort4 gr_nxt = *(const ushort4*)&gb[(size_t)nstep * 2048];

        // phase 1: MFMA  P = bf16(h) @ bf16(Whh)  (1-term)
        f32x4 acc[4] = {};
        #pragma unroll
        for (int ks = 0; ks < 4; ++ks) {
            s16x8 ah = *(const s16x8*)&Ah[l15 * AHS + ks * 32 + quad * 8];
            #pragma unroll
            for (int nt = 0; nt < 4; ++nt)
                acc[nt] = __builtin_amdgcn_mfma_f32_16x16x32_bf16(ah, bh[nt][ks], acc[nt], 0, 0, 0);
        }

        // intra-wave exchange: quad-0 lanes hold rows 0..3 (the real seqs)
        if (quad == 0) {
            #pragma unroll
            for (int nt = 0; nt < 4; ++nt)
                #pragma unroll
                for (int r = 0; r < 4; ++r)
                    partw[wave][r][nt * 16 + l15] = acc[nt][r];
        }
        // same-wave producer/consumer: compiler inserts lgkmcnt wait, no barrier

        // phase 2: LSTM cell for (b2, jj); reads this wave's own patch
        {
            float4 pa = *(const float4*)&partw[wave][b2][l15 * 4];
            float xi = pa.x + bf2f(gr_cur.x);
            float xf = pa.y + bf2f(gr_cur.y);
            float xg = pa.z + bf2f(gr_cur.z);
            float xo = pa.w + bf2f(gr_cur.w);
            float ii = sigf(xi), ff = sigf(xf), gg = tanhfast(xg), oo = sigf(xo);
            float cn = ff * c + ii * gg;
            c = cn;
            float hn = oo * tanhfast(cn);
            hn_last = hn;
            unsigned short hh = f2bf(hn);
            Ah[b2 * AHS + jj] = hh;
            if (hptr) {
                *hptr = hh;
                hptr += 128;
            }
        }
        gr_cur = gr_nxt;
        // LDS-only barrier: Ah writes visible to all waves; globals in flight
        barrier_lds_only();
    }

    // fused FC head (layer 1): out[bg] = dot(h_last[bg], fcw) + fcb
    if (outp) {
        float* red = (float*)Ah;   // 2 KiB scratch, Ah is dead now
        red[b2 * 128 + jj] = hn_last * fcw[jj];
        __syncthreads();
        if (wave < 4) {            // wave w reduces sequence b0+w
            float v = red[wave * 128 + lane] + red[wave * 128 + lane + 64];
            #pragma unroll
            for (int off = 32; off > 0; off >>= 1)
                v += __shfl_down(v, off);
            if (lane == 0) outp[b0 + wave] = v + fcb[0];
        }
    }
}

// ---------------------------------------------------------------- launch
extern "C" void kernel_launch(void* const* d_in, const int* in_sizes, int n_in,
                              void* d_out, int out_size, void* d_ws, size_t ws_size,
                              hipStream_t stream)
{
    const float* x    = (const float*)d_in[0];
    const int*   ei   = (const int*)d_in[1];
    const float* W1   = (const float*)d_in[3];
    const float* b1   = (const float*)d_in[4];
    const float* W2   = (const float*)d_in[5];
    const float* b2   = (const float*)d_in[6];
    const float* fcw  = (const float*)d_in[7];
    const float* fcb  = (const float*)d_in[8];
    const float* wih0 = (const float*)d_in[9];
    const float* whh0 = (const float*)d_in[10];
    const float* bih0 = (const float*)d_in[11];
    const float* bhh0 = (const float*)d_in[12];
    const float* wih1 = (const float*)d_in[13];
    const float* whh1 = (const float*)d_in[14];
    const float* bih1 = (const float*)d_in[15];
    const float* bhh1 = (const float*)d_in[16];
    float* out = (float*)d_out;

    char* ws = (char*)d_ws;
    // ---- persistent regions
    unsigned short* shi = (unsigned short*)(ws + 0);          // 12.8 MB
    unsigned short* bufG = (unsigned short*)(ws + 51200000);  // 51.2 MB bf16 (ends 102.4M)

    // ---- GCN-phase regions (overlap bufG region; dead before gate GEMM writes)
    unsigned short* xhi = (unsigned short*)(ws + 51200000);   // 12.8 MB
    unsigned short* bufHg = (unsigned short*)(ws + 76800000); // 12.8 MB bf16 h
    int* cnt      = (int*)(ws + 102400000);                   // 200000 B (pad 204800)
    int* cursor   = (int*)(ws + 102604800);                   // contiguous with cnt
    int* rowstart = (int*)(ws + 102809600);
    int* adj      = (int*)(ws + 103014400);                   // 2.4 MB (ends 105.42M)
    int* bsum     = (int*)(ws + 105420800);                   // NSCB ints

    float* dinv = (float*)(ws + 153600000);
    float* bp0  = (float*)(ws + 153800192);
    float* bp1  = (float*)(ws + 153802240);
    unsigned short* w1t_hi   = (unsigned short*)(ws + 153804288);
    unsigned short* w1t_lo   = (unsigned short*)(ws + 153837056);
    unsigned short* w2t_hi   = (unsigned short*)(ws + 153869824);
    unsigned short* w2t_lo   = (unsigned short*)(ws + 153902592);
    unsigned short* wpih0_hi = (unsigned short*)(ws + 153935360);
    unsigned short* wpih0_lo = (unsigned short*)(ws + 154066432);
    unsigned short* wpih1_hi = (unsigned short*)(ws + 154197504);
    unsigned short* wpih1_lo = (unsigned short*)(ws + 154328576);
    unsigned short* wphh0_hi = (unsigned short*)(ws + 154459648);
    unsigned short* wphh0_lo = (unsigned short*)(ws + 154590720);
    unsigned short* wphh1_hi = (unsigned short*)(ws + 154721792);
    unsigned short* wphh1_lo = (unsigned short*)(ws + 154852864);

    // ---- CSR build + dinv (multi-block scan); cnt+cursor zeroed in ONE memset
    hipMemsetAsync(cnt, 0, 409600, stream);
    k_count<<<(NE + 255) / 256, 256, 0, stream>>>(ei, cnt);
    k_bsum<<<NSCB, 256, 0, stream>>>(cnt, bsum);
    k_bscan<<<1, 256, 0, stream>>>(bsum);
    k_bout<<<NSCB, 256, 0, stream>>>(cnt, bsum, rowstart, dinv);
    k_fill<<<(NE + 255) / 256, 256, 0, stream>>>(ei, rowstart, cursor, adj);

    // ---- weight prep
    k_prep_gcnw2<<<128, 256, 0, stream>>>(W1, W2, w1t_hi, w1t_lo, w2t_hi, w2t_lo);
    k_prep_lstm<<<514, 256, 0, stream>>>(wih0, whh0, bih0, bhh0,
                                         wpih0_hi, wpih0_lo, wphh0_hi, wphh0_lo, bp0);
    k_prep_lstm<<<514, 256, 0, stream>>>(wih1, whh1, bih1, bhh1,
                                         wpih1_hi, wpih1_lo, wphh1_hi, wphh1_lo, bp1);

    dim3 gH(1, 391);     // GCN GEMMs: 128-row panel, NT=2 (128 cols)
    const int gGate = (NND + 255) / 256;   // 196 blocks of 256 rows (4 panels)

    // ---- GCN layer 1 (fp32 A, convert-on-stage, split precision; bf16 h out)
    k_gemm_mfma_xa<<<gH, 256, 0, stream>>>(x, w1t_hi, w1t_lo, nullptr, bufHg, NND, 128, 2);
    k_gather<<<NND / 4, 256, 0, stream>>>(rowstart, adj, bufHg, dinv, b1, xhi);

    // ---- GCN layer 2 (2-term: A = bf16 hi only; bf16 h out)
    k_gemm_mfma_h2<<<gH, 256, 0, stream>>>(xhi, w2t_hi, w2t_lo, nullptr, bufHg, NND, 128, 2);
    k_gather<<<NND / 4, 256, 0, stream>>>(rowstart, adj, bufHg, dinv, b2, shi);

    // ---- LSTM layer 0: W-amortized gate GEMM (bf16 G) + recurrence
    k_gemm_gT_h<<<gGate, 512, 0, stream>>>(shi, wpih0_hi, wpih0_lo, bp0, bufG, NND);
    k_lstm<<<NB / SB, 512, 0, stream>>>(bufG, wphh0_hi, shi,
                                        nullptr, nullptr, nullptr);

    // ---- LSTM layer 1: W-amortized gate GEMM (bf16 G) + recurrence + fused FC
    k_gemm_gT_h<<<gGate, 512, 0, stream>>>(shi, wpih1_hi, wpih1_lo, bp1, bufG, NND);
    k_lstm<<<NB / SB, 512, 0, stream>>>(bufG, wphh1_hi, nullptr,
                                        fcw, fcb, out);
}